// Round 3
// baseline (387.059 us; speedup 1.0000x reference)
//
#include <hip/hip_runtime.h>
#include <hip/hip_bf16.h>

#define NTOT 2048
#define DD 256
#define BSZ 4

typedef _Float16 half_t;
typedef __attribute__((ext_vector_type(8))) _Float16 halfx8;
typedef __attribute__((ext_vector_type(4))) _Float16 halfx4;
typedef __attribute__((ext_vector_type(4))) float f32x4;

// ---------------- block reduce (256 threads) ----------------
__device__ __forceinline__ float blockReduceSum256(float v) {
    __shared__ float red[4];
    for (int off = 32; off > 0; off >>= 1) v += __shfl_down(v, off);
    int lane = threadIdx.x & 63, w = threadIdx.x >> 6;
    __syncthreads();                 // protect red[] reuse across successive calls
    if (lane == 0) red[w] = v;
    __syncthreads();
    return red[0] + red[1] + red[2] + red[3];
}

// ---------------- pos stats: mean/scale for 3 cols ----------------
__global__ void pos_stats_kernel(const float* __restrict__ pos, float* __restrict__ stats) {
    int tid = threadIdx.x;
    float s[3] = {0.f, 0.f, 0.f};
    for (int i = tid; i < NTOT; i += 256)
        for (int c = 0; c < 3; ++c) s[c] += pos[i * 3 + c];
    float m[3];
    for (int c = 0; c < 3; ++c) m[c] = blockReduceSum256(s[c]) / (float)NTOT;
    float q[3] = {0.f, 0.f, 0.f};
    for (int i = tid; i < NTOT; i += 256)
        for (int c = 0; c < 3; ++c) { float d = pos[i * 3 + c] - m[c]; q[c] += d * d; }
    for (int c = 0; c < 3; ++c) {
        float t = blockReduceSum256(q[c]);
        if (tid == 0) {
            float var = ((float)BSZ * t) / ((float)BSZ * NTOT - 1.0f);
            stats[c] = m[c];
            stats[3 + c] = 1.0f / (sqrtf(var) + 1e-8f);
        }
    }
}

// 1/||p|| for each pooling depth
__global__ void pnorm_kernel(const float* __restrict__ poolp, float* __restrict__ pinv) {
    int dep = blockIdx.x, tid = threadIdx.x;
    float v = poolp[dep * DD + tid];
    float ss = blockReduceSum256(v * v);
    if (tid == 0) pinv[dep] = rsqrtf(ss);
}

// q[i,d] = silu(pn[i,:] @ pw1[:,d] + pb1[d])  -> f16
__global__ void pe_q_kernel(const float* __restrict__ pos, const float* __restrict__ stats,
                            const float* __restrict__ pw1, const float* __restrict__ pb1,
                            half_t* __restrict__ q) {
    int i = blockIdx.x, d = threadIdx.x;
    float acc = pb1[d];
    for (int c = 0; c < 3; ++c) {
        float pn = (pos[i * 3 + c] - stats[c]) * stats[3 + c];
        acc += pn * pw1[c * DD + d];
    }
    acc = acc / (1.0f + expf(-acc));
    q[i * DD + d] = (half_t)acc;
}

// h[row,d] = x[row,:16] @ in_w[:,d] + in_b[d] + pe[row % N, d]; + row stats
__global__ void init_h_kernel(const float* __restrict__ x, const float* __restrict__ in_w,
                              const float* __restrict__ in_b, const float* __restrict__ pe,
                              float* __restrict__ h, float* __restrict__ stats) {
    int row = blockIdx.x, d = threadIdx.x;
    float acc = in_b[d];
    for (int k = 0; k < 16; ++k) acc += x[row * 16 + k] * in_w[k * DD + d];
    float v = acc + pe[(row & (NTOT - 1)) * DD + d];
    h[row * DD + d] = v;
    float s = blockReduceSum256(v);
    float ss = blockReduceSum256(v * v);
    if (d == 0) {
        float mean = s * (1.0f / DD);
        float var = ss * (1.0f / DD) - mean * mean;
        stats[2 * row] = mean;
        stats[2 * row + 1] = rsqrtf(var + 1e-5f);
    }
}

// ---------------- weight prep: Wt[m][n][k] = f16(W_m[k][n]) ----------------
// m 0..7 = bw1, 8..15 = bw2, 16 = pw2
__global__ void wprep_kernel(const float* __restrict__ bw1, const float* __restrict__ bw2,
                             const float* __restrict__ pw2, half_t* __restrict__ Wt) {
    int m = blockIdx.x, nb = blockIdx.y * 16, kb = blockIdx.z * 16;
    const float* W = (m < 8) ? (bw1 + (size_t)m * DD * DD)
                  : (m < 16) ? (bw2 + (size_t)(m - 8) * DD * DD)
                             : pw2;
    __shared__ float s[16][17];
    int i = threadIdx.x >> 4, j = threadIdx.x & 15;
    s[i][j] = W[(size_t)(kb + i) * DD + nb + j];
    __syncthreads();
    Wt[(size_t)m * DD * DD + (size_t)(nb + i) * DD + kb + j] = (half_t)s[j][i];
}

// ---------------- CSR build (deterministic) ----------------
__global__ void csr_count_kernel(const float* __restrict__ adj, int* __restrict__ counts) {
    int i = blockIdx.x, tid = threadIdx.x;
    float c = 0.f;
    for (int j = tid; j < NTOT; j += 256) c += (adj[i * NTOT + j] != 0.f) ? 1.f : 0.f;
    float t = blockReduceSum256(c);
    if (tid == 0) counts[i] = (int)(t + 0.5f);
}

__global__ void scan_kernel(const int* __restrict__ counts, int* __restrict__ row_ptr) {
    __shared__ int csum[256];
    int tid = threadIdx.x;
    int local[8]; int tot = 0;
    for (int u = 0; u < 8; ++u) { local[u] = counts[tid * 8 + u]; tot += local[u]; }
    csum[tid] = tot; __syncthreads();
    for (int off = 1; off < 256; off <<= 1) {
        int v = (tid >= off) ? csum[tid - off] : 0;
        __syncthreads();
        csum[tid] += v;
        __syncthreads();
    }
    int run = csum[tid] - tot;  // exclusive prefix
    for (int u = 0; u < 8; ++u) { row_ptr[tid * 8 + u] = run; run += local[u]; }
    if (tid == 255) row_ptr[NTOT] = run;
}

__global__ void csr_fill_kernel(const float* __restrict__ adj, const int* __restrict__ row_ptr,
                                int* __restrict__ col) {
    int i = blockIdx.x, lane = threadIdx.x;  // 64 threads
    int base = row_ptr[i];
    int run = 0;
    for (int j0 = 0; j0 < NTOT; j0 += 64) {
        int j = j0 + lane;
        bool pred = adj[i * NTOT + j] != 0.f;
        unsigned long long mask = __ballot(pred);
        if (pred) {
            int pos = run + __popcll(mask & ((1ull << lane) - 1ull));
            col[base + pos] = j;
        }
        run += __popcll(mask);
    }
}

// ---------------- maps (tag-encoded inverse: inv = tag<<12 | local_idx) ----------------
__global__ void init_maps_kernel(int* __restrict__ orig, int* __restrict__ inv) {
    int t = blockIdx.x * 256 + threadIdx.x;  // B*N
    int i = t & (NTOT - 1);
    orig[t] = i; inv[t] = i;  // tag 0
}
__global__ void inv_set_kernel(const int* __restrict__ orig, int* __restrict__ inv, int k, int tag) {
    int t = blockIdx.x * 256 + threadIdx.x;  // B*k (exact multiple of 256)
    int b = t / k, r = t - b * k;
    inv[b * NTOT + orig[b * NTOT + r]] = (tag << 12) | r;
}

// ---------------- fused LN + sparse aggregation -> f16 ----------------
// t[d] = g[d]*( eps1*(h_s-m_s)*rs_s + sum_j (h_j-m_j)*rs_j ) + (eps1+cnt)*b[d]
__global__ void __launch_bounds__(256) agg_kernel(
    const float* __restrict__ h, const float* __restrict__ stats, half_t* __restrict__ t,
    const float* __restrict__ g, const float* __restrict__ b,
    const int* __restrict__ row_ptr, const int* __restrict__ col,
    const int* __restrict__ orig, const int* __restrict__ inv,
    const float* __restrict__ beps, int blk, int n, int tag) {
    int w = threadIdx.x >> 6, lane = threadIdx.x & 63;
    int r = blockIdx.x * 4 + w;      // 0..B*n-1
    int bb = r / n, i = r - bb * n;
    const f32x4* h4 = (const f32x4*)h;
    const f32x4* hb4 = h4 + (size_t)bb * n * 64;
    float eps1 = 1.0f + beps[blk];
    float ms = stats[2 * r], rs = stats[2 * r + 1];
    f32x4 acc = h4[(size_t)r * 64 + lane] * (eps1 * rs);
    float C = eps1 * rs * ms;
    float coefb = eps1;
    int o = orig[bb * NTOT + i];
    int s0 = row_ptr[o], e0 = row_ptr[o + 1];
    const int* invb = inv + bb * NTOT;
    for (int p = s0; p < e0; ++p) {
        int v = invb[col[p]];
        if ((v >> 12) == tag) {
            int j = v & 4095;
            int rj = bb * n + j;
            float rsj = stats[2 * rj + 1];
            acc += hb4[(size_t)j * 64 + lane] * rsj;
            C += rsj * stats[2 * rj];
            coefb += 1.0f;
        }
    }
    f32x4 gv = ((const f32x4*)g)[lane];
    f32x4 bv = ((const f32x4*)b)[lane];
    f32x4 tv = gv * (acc - C) + bv * coefb;
    halfx4 th;
    for (int u = 0; u < 4; ++u) th[u] = (half_t)tv[u];
    ((halfx4*)t)[(size_t)r * 64 + lane] = th;
}

// ---------------- f16 MFMA matmul: block owns 32 rows x 256 cols ----------------
// A f16 [rows][256]; Wt f16 [256][256] with Wt[n][k] = W[k][n]. 256 thr = 4 waves,
// wave w -> cols [64w, 64w+64). MODE 0: f32 store; 1: silu->f16; 2: h += v, + row
// stats (mean,rstd) and optional pool score.
template <int MODE, int SCORE>
__global__ void __launch_bounds__(256) mm_f16(
    const half_t* __restrict__ A, const half_t* __restrict__ Wt,
    const float* __restrict__ bias, void* __restrict__ Cout,
    float* __restrict__ hres, float* __restrict__ stats,
    const float* __restrict__ poolp, const float* __restrict__ pinv_all,
    float* __restrict__ scores, int dep, int n) {
    __shared__ float part[4][32][3];
    int tid = threadIdx.x;
    int w = tid >> 6, l = tid & 63;
    int lo = l & 15, hi = l >> 4;
    int rowBase = blockIdx.x * 32;
    int kb = hi * 8;
    const half_t* a0p = A + (size_t)(rowBase + lo) * DD + kb;
    const half_t* a1p = a0p + 16 * DD;
    int c0 = w * 64 + lo;
    f32x4 acc[2][4] = {};
#pragma unroll
    for (int k0 = 0; k0 < DD; k0 += 32) {
        halfx8 a0 = *(const halfx8*)(a0p + k0);
        halfx8 a1 = *(const halfx8*)(a1p + k0);
#pragma unroll
        for (int j = 0; j < 4; ++j) {
            halfx8 bj = *(const halfx8*)(Wt + (size_t)(c0 + 16 * j) * DD + kb + k0);
            acc[0][j] = __builtin_amdgcn_mfma_f32_16x16x32_f16(a0, bj, acc[0][j], 0, 0, 0);
            acc[1][j] = __builtin_amdgcn_mfma_f32_16x16x32_f16(a1, bj, acc[1][j], 0, 0, 0);
        }
    }
    // C/D layout (HW-verified): col = lo, row = hi*4 + q (+16 per i)
    float bs[4];
#pragma unroll
    for (int j = 0; j < 4; ++j) bs[j] = bias[w * 64 + j * 16 + lo];
    if (MODE == 0 || MODE == 1) {
#pragma unroll
        for (int i = 0; i < 2; ++i)
#pragma unroll
            for (int q = 0; q < 4; ++q) {
                int r = rowBase + i * 16 + hi * 4 + q;
#pragma unroll
                for (int j = 0; j < 4; ++j) {
                    int c = w * 64 + j * 16 + lo;
                    float v = acc[i][j][q] + bs[j];
                    if (MODE == 0) {
                        ((float*)Cout)[(size_t)r * DD + c] = v;
                    } else {
                        v = v / (1.0f + expf(-v));
                        ((half_t*)Cout)[(size_t)r * DD + c] = (half_t)v;
                    }
                }
            }
    } else {
        float pinv = 0.f, pv[4];
        if (SCORE) {
            pinv = pinv_all[dep];
#pragma unroll
            for (int j = 0; j < 4; ++j) pv[j] = poolp[dep * DD + w * 64 + j * 16 + lo];
        }
#pragma unroll
        for (int i = 0; i < 2; ++i)
#pragma unroll
            for (int q = 0; q < 4; ++q) {
                int r = rowBase + i * 16 + hi * 4 + q;
                float s = 0.f, ss = 0.f, sp = 0.f;
#pragma unroll
                for (int j = 0; j < 4; ++j) {
                    int c = w * 64 + j * 16 + lo;
                    size_t idx = (size_t)r * DD + c;
                    float vh = hres[idx] + acc[i][j][q] + bs[j];
                    hres[idx] = vh;
                    s += vh; ss += vh * vh;
                    if (SCORE) sp += vh * pv[j];
                }
#pragma unroll
                for (int m = 1; m < 16; m <<= 1) {
                    s += __shfl_xor(s, m);
                    ss += __shfl_xor(ss, m);
                    if (SCORE) sp += __shfl_xor(sp, m);
                }
                if (lo == 0) {
                    int rl = i * 16 + hi * 4 + q;
                    part[w][rl][0] = s; part[w][rl][1] = ss;
                    if (SCORE) part[w][rl][2] = sp;
                }
            }
        __syncthreads();
        if (tid < 32) {
            float s = 0.f, ss = 0.f, sp = 0.f;
#pragma unroll
            for (int w2 = 0; w2 < 4; ++w2) {
                s += part[w2][tid][0]; ss += part[w2][tid][1];
                if (SCORE) sp += part[w2][tid][2];
            }
            int r = rowBase + tid;
            float mean = s * (1.0f / DD);
            float var = ss * (1.0f / DD) - mean * mean;
            stats[2 * r] = mean;
            stats[2 * r + 1] = rsqrtf(var + 1e-5f);
            if (SCORE) {
                int b2 = r / n, ii = r - b2 * n;
                scores[b2 * NTOT + ii] = sp * pinv;
            }
        }
    }
}

// ---------------- pooling ----------------
// radix-select threshold (k-th largest) + tie-aware stable compaction
__global__ void topk_kernel(const float* __restrict__ scores, const int* __restrict__ orig_cur,
                            int* __restrict__ orig_next, int* __restrict__ idx_local,
                            float* __restrict__ gate, int n, int k) {
    __shared__ unsigned keys[2048];
    __shared__ int hist[256];
    __shared__ int sg[256], se[256];
    __shared__ int sh_bucket, sh_r;
    int b = blockIdx.x;
    const float* sc = scores + b * NTOT;
    int tid = threadIdx.x;
    for (int i = tid; i < n; i += 256) {
        unsigned u = __float_as_uint(sc[i]);
        keys[i] = (u & 0x80000000u) ? ~u : (u | 0x80000000u);
    }
    if (tid == 0) sh_r = n - k;  // 0-indexed rank in ascending order
    __syncthreads();
    unsigned prefix = 0;
    for (int shift = 24; shift >= 0; shift -= 8) {
        hist[tid] = 0;
        __syncthreads();
        unsigned mask = (shift == 24) ? 0u : (0xFFFFFFFFu << (shift + 8));
        for (int i = tid; i < n; i += 256) {
            unsigned key = keys[i];
            if ((key & mask) == (prefix & mask))
                atomicAdd(&hist[(key >> shift) & 255], 1);
        }
        __syncthreads();
        int cnt = hist[tid];
        sg[tid] = cnt;
        __syncthreads();
        for (int off = 1; off < 256; off <<= 1) {
            int v = (tid >= off) ? sg[tid - off] : 0;
            __syncthreads();
            sg[tid] += v;
            __syncthreads();
        }
        int incl = sg[tid], excl = incl - cnt;
        int r = sh_r;
        if (excl <= r && r < incl) { sh_bucket = tid; sh_r = r - excl; }
        __syncthreads();
        prefix |= ((unsigned)sh_bucket) << shift;
        __syncthreads();
    }
    unsigned uthr = (prefix & 0x80000000u) ? (prefix ^ 0x80000000u) : ~prefix;
    float thr = __uint_as_float(uthr);  // exact k-th largest value
    int chunk = n / 256;
    int base = tid * chunk;
    int cgt = 0, ceq = 0;
    for (int u = 0; u < chunk; ++u) {
        float s = sc[base + u];
        cgt += (s > thr); ceq += (s == thr);
    }
    sg[tid] = cgt; se[tid] = ceq; __syncthreads();
    for (int off = 1; off < 256; off <<= 1) {
        int vg = (tid >= off) ? sg[tid - off] : 0;
        int ve = (tid >= off) ? se[tid - off] : 0;
        __syncthreads();
        sg[tid] += vg; se[tid] += ve;
        __syncthreads();
    }
    int total_gt = sg[255];
    int ties = k - total_gt;             // how many ==thr to take (lowest indices first)
    int gtb = sg[tid] - cgt, eqb = se[tid] - ceq;  // exclusive prefixes
    for (int u = 0; u < chunk; ++u) {
        int i = base + u;
        float s = sc[i];
        bool isgt = (s > thr), iseq = (s == thr);
        bool keep = isgt || (iseq && eqb < ties);
        if (keep) {
            int pos = gtb + (eqb < ties ? eqb : ties);  // kept-before-i
            idx_local[b * NTOT + pos] = i;
            gate[b * NTOT + pos] = tanhf(s);
            orig_next[b * NTOT + pos] = orig_cur[b * NTOT + i];
        }
        gtb += isgt; eqb += iseq;
    }
}

__global__ void __launch_bounds__(64) gather_kernel(
    const float* __restrict__ h, const int* __restrict__ idx_local,
    const float* __restrict__ gate, float* __restrict__ hout,
    float* __restrict__ stats, int n_old, int k) {
    int r = blockIdx.x;  // B*k
    int b = r / k, rr = r - b * k;
    int lane = threadIdx.x;
    int src = idx_local[b * NTOT + rr];
    float gg = gate[b * NTOT + rr];
    f32x4 v = ((const f32x4*)h)[(size_t)(b * n_old + src) * 64 + lane] * gg;
    ((f32x4*)hout)[(size_t)r * 64 + lane] = v;
    float s = v[0] + v[1] + v[2] + v[3];
    float ss = v[0] * v[0] + v[1] * v[1] + v[2] * v[2] + v[3] * v[3];
#pragma unroll
    for (int m = 1; m < 64; m <<= 1) { s += __shfl_xor(s, m); ss += __shfl_xor(ss, m); }
    if (lane == 0) {
        float mean = s * (1.0f / DD);
        float var = ss * (1.0f / DD) - mean * mean;
        stats[2 * r] = mean;
        stats[2 * r + 1] = rsqrtf(var + 1e-5f);
    }
}

// ---------------- readout ----------------
__global__ void readout_kernel(const float* __restrict__ h, float* __restrict__ feat) {
    int bd = blockIdx.x;  // B*256
    int b = bd >> 8, d = bd & 255;
    int i = threadIdx.x;  // node (n=256)
    float x = h[(size_t)(b * 256 + i) * DD + d];
    float m = blockReduceSum256(x) / 256.0f;
    float diff = x - m;
    float s2 = blockReduceSum256(diff * diff);
    if (i == 0) {
        feat[b * 512 + d] = m;
        feat[b * 512 + 256 + d] = sqrtf(s2 / 255.0f) + 1e-6f;  // ddof=1
    }
}

__global__ void final_kernel(const float* __restrict__ feat, const float* __restrict__ lw,
                             const float* __restrict__ lb, float* __restrict__ out) {
    int b = blockIdx.x, l = threadIdx.x;  // 128 threads
    float acc = lb[l];
    const float* f = feat + b * 512;
    for (int k = 0; k < 512; ++k) acc += f[k] * lw[k * 128 + l];
    out[b * 128 + l] = acc;
}

extern "C" void kernel_launch(void* const* d_in, const int* in_sizes, int n_in,
                              void* d_out, int out_size, void* d_ws, size_t ws_size,
                              hipStream_t stream) {
    (void)in_sizes; (void)n_in; (void)out_size; (void)ws_size;
    const float* x     = (const float*)d_in[0];
    const float* adj   = (const float*)d_in[1];
    const float* pos   = (const float*)d_in[2];
    const float* in_w  = (const float*)d_in[3];
    const float* in_b  = (const float*)d_in[4];
    const float* pw1   = (const float*)d_in[5];
    const float* pb1   = (const float*)d_in[6];
    const float* pw2   = (const float*)d_in[7];
    const float* pb2   = (const float*)d_in[8];
    const float* bg    = (const float*)d_in[9];
    const float* bb    = (const float*)d_in[10];
    const float* bw1   = (const float*)d_in[11];
    const float* bb1   = (const float*)d_in[12];
    const float* bw2   = (const float*)d_in[13];
    const float* bb2   = (const float*)d_in[14];
    const float* beps  = (const float*)d_in[15];
    const float* poolp = (const float*)d_in[16];
    const float* lw    = (const float*)d_in[17];
    const float* lb    = (const float*)d_in[18];
    float* out = (float*)d_out;

    char* wp = (char*)d_ws;
    auto alloc = [&](size_t bytes) -> void* {
        void* p = (void*)wp;
        wp += (bytes + 255) & ~(size_t)255;
        return p;
    };
    const size_t HBYTES = (size_t)BSZ * NTOT * DD * sizeof(float);  // 8.39 MB
    float*  h    = (float*)alloc(HBYTES);
    float*  bufC = (float*)alloc(HBYTES);          // pe out / gather target (f32)
    half_t* tb   = (half_t*)alloc(HBYTES / 2);     // agg out / pe q (f16)
    half_t* ub   = (half_t*)alloc(HBYTES / 2);     // mm1 out (f16)
    half_t* Wt   = (half_t*)alloc((size_t)17 * DD * DD * sizeof(half_t));
    float* stats   = (float*)alloc((size_t)BSZ * NTOT * 2 * sizeof(float));
    float* pstats  = (float*)alloc(8 * sizeof(float));
    float* pinv    = (float*)alloc(4 * sizeof(float));
    float* scores  = (float*)alloc(BSZ * NTOT * sizeof(float));
    float* gate    = (float*)alloc(BSZ * NTOT * sizeof(float));
    int*   origA   = (int*)alloc(BSZ * NTOT * sizeof(int));
    int*   origB   = (int*)alloc(BSZ * NTOT * sizeof(int));
    int*   idxl    = (int*)alloc(BSZ * NTOT * sizeof(int));
    int*   inv     = (int*)alloc(BSZ * NTOT * sizeof(int));
    int*   counts  = (int*)alloc(NTOT * sizeof(int));
    int*   row_ptr = (int*)alloc((NTOT + 1) * sizeof(int));
    int*   col     = (int*)alloc((size_t)NTOT * 64 * sizeof(int));
    float* feat    = (float*)alloc(BSZ * 512 * sizeof(float));

    // ---- weight prep (f16 transposed) + pool norms ----
    wprep_kernel<<<dim3(17, 16, 16), 256, 0, stream>>>(bw1, bw2, pw2, Wt);
    pnorm_kernel<<<3, 256, 0, stream>>>(poolp, pinv);
    // ---- positional embedding ----
    pos_stats_kernel<<<1, 256, 0, stream>>>(pos, pstats);
    pe_q_kernel<<<NTOT, 256, 0, stream>>>(pos, pstats, pw1, pb1, tb);
    mm_f16<0, 0><<<NTOT / 32, 256, 0, stream>>>(tb, Wt + (size_t)16 * DD * DD, pb2, bufC,
                                                nullptr, nullptr, nullptr, nullptr, nullptr, 0, NTOT);
    // ---- h init (+ row stats) ----
    init_h_kernel<<<BSZ * NTOT, 256, 0, stream>>>(x, in_w, in_b, bufC, h, stats);
    // ---- CSR of original adjacency ----
    csr_count_kernel<<<NTOT, 256, 0, stream>>>(adj, counts);
    scan_kernel<<<1, 256, 0, stream>>>(counts, row_ptr);
    csr_fill_kernel<<<NTOT, 64, 0, stream>>>(adj, row_ptr, col);
    // ---- index maps ----
    init_maps_kernel<<<(BSZ * NTOT) / 256, 256, 0, stream>>>(origA, inv);

    float* hcur = h;
    float* halt = bufC;
    int* orig = origA;
    int* orign = origB;
    int n = NTOT;
    int blk = 0;
    for (int dep = 0; dep < 4; ++dep) {
        for (int s = 0; s < 2; ++s) {
            int rows = BSZ * n;
            agg_kernel<<<rows / 4, 256, 0, stream>>>(hcur, stats, tb, bg + blk * DD, bb + blk * DD,
                                                     row_ptr, col, orig, inv, beps, blk, n, dep);
            mm_f16<1, 0><<<rows / 32, 256, 0, stream>>>(
                tb, Wt + (size_t)blk * DD * DD, bb1 + blk * DD, ub,
                nullptr, nullptr, nullptr, nullptr, nullptr, 0, n);
            if (s == 1 && dep < 3) {
                mm_f16<2, 1><<<rows / 32, 256, 0, stream>>>(
                    ub, Wt + (size_t)(8 + blk) * DD * DD, bb2 + blk * DD, nullptr,
                    hcur, stats, poolp, pinv, scores, dep, n);
            } else {
                mm_f16<2, 0><<<rows / 32, 256, 0, stream>>>(
                    ub, Wt + (size_t)(8 + blk) * DD * DD, bb2 + blk * DD, nullptr,
                    hcur, stats, nullptr, nullptr, nullptr, 0, n);
            }
            ++blk;
        }
        if (dep < 3) {
            int k = n / 2;
            topk_kernel<<<BSZ, 256, 0, stream>>>(scores, orig, orign, idxl, gate, n, k);
            gather_kernel<<<BSZ * k, 64, 0, stream>>>(hcur, idxl, gate, halt, stats, n, k);
            { float* t = hcur; hcur = halt; halt = t; }
            { int* t = orig; orig = orign; orign = t; }
            inv_set_kernel<<<(BSZ * k) / 256, 256, 0, stream>>>(orig, inv, k, dep + 1);
            n = k;
        }
    }
    // ---- readout ----
    readout_kernel<<<BSZ * 256, 256, 0, stream>>>(hcur, feat);
    final_kernel<<<BSZ, 128, 0, stream>>>(feat, lw, lb, out);
}

// Round 4
// 384.880 us; speedup vs baseline: 1.0057x; 1.0057x over previous
//
#include <hip/hip_runtime.h>
#include <hip/hip_bf16.h>

#define NTOT 2048
#define DD 256
#define BSZ 4

typedef _Float16 half_t;
typedef __attribute__((ext_vector_type(8))) _Float16 halfx8;
typedef __attribute__((ext_vector_type(4))) _Float16 halfx4;
typedef __attribute__((ext_vector_type(4))) float f32x4;

// ---------------- block reduce (256 threads) ----------------
__device__ __forceinline__ float blockReduceSum256(float v) {
    __shared__ float red[4];
    for (int off = 32; off > 0; off >>= 1) v += __shfl_down(v, off);
    int lane = threadIdx.x & 63, w = threadIdx.x >> 6;
    __syncthreads();
    if (lane == 0) red[w] = v;
    __syncthreads();
    return red[0] + red[1] + red[2] + red[3];
}

// ---------------- pos stats ----------------
__global__ void pos_stats_kernel(const float* __restrict__ pos, float* __restrict__ stats) {
    int tid = threadIdx.x;
    float s[3] = {0.f, 0.f, 0.f};
    for (int i = tid; i < NTOT; i += 256)
        for (int c = 0; c < 3; ++c) s[c] += pos[i * 3 + c];
    float m[3];
    for (int c = 0; c < 3; ++c) m[c] = blockReduceSum256(s[c]) / (float)NTOT;
    float q[3] = {0.f, 0.f, 0.f};
    for (int i = tid; i < NTOT; i += 256)
        for (int c = 0; c < 3; ++c) { float d = pos[i * 3 + c] - m[c]; q[c] += d * d; }
    for (int c = 0; c < 3; ++c) {
        float t = blockReduceSum256(q[c]);
        if (tid == 0) {
            float var = ((float)BSZ * t) / ((float)BSZ * NTOT - 1.0f);
            stats[c] = m[c];
            stats[3 + c] = 1.0f / (sqrtf(var) + 1e-8f);
        }
    }
}

__global__ void pnorm_kernel(const float* __restrict__ poolp, float* __restrict__ pinv) {
    int dep = blockIdx.x, tid = threadIdx.x;
    float v = poolp[dep * DD + tid];
    float ss = blockReduceSum256(v * v);
    if (tid == 0) pinv[dep] = rsqrtf(ss);
}

// q[i,d] = silu(pn@pw1 + pb1) -> f16
__global__ void pe_q_kernel(const float* __restrict__ pos, const float* __restrict__ stats,
                            const float* __restrict__ pw1, const float* __restrict__ pb1,
                            half_t* __restrict__ q) {
    int i = blockIdx.x, d = threadIdx.x;
    float acc = pb1[d];
    for (int c = 0; c < 3; ++c) {
        float pn = (pos[i * 3 + c] - stats[c]) * stats[3 + c];
        acc += pn * pw1[c * DD + d];
    }
    acc = acc / (1.0f + expf(-acc));
    q[i * DD + d] = (half_t)acc;
}

// h = x@in_w + in_b + pe; also write z = (h-m)*rstd
__global__ void init_h_kernel(const float* __restrict__ x, const float* __restrict__ in_w,
                              const float* __restrict__ in_b, const float* __restrict__ pe,
                              float* __restrict__ h, float* __restrict__ z) {
    int row = blockIdx.x, d = threadIdx.x;
    float acc = in_b[d];
    for (int k = 0; k < 16; ++k) acc += x[row * 16 + k] * in_w[k * DD + d];
    float v = acc + pe[(row & (NTOT - 1)) * DD + d];
    h[(size_t)row * DD + d] = v;
    float s = blockReduceSum256(v);
    float ss = blockReduceSum256(v * v);
    float mean = s * (1.0f / DD);
    float rs = rsqrtf(ss * (1.0f / DD) - mean * mean + 1e-5f);
    z[(size_t)row * DD + d] = (v - mean) * rs;
}

// ---------------- weight prep: Wt[m][n][k] = f16(W_m[k][n]) ----------------
__global__ void wprep_kernel(const float* __restrict__ bw1, const float* __restrict__ bw2,
                             const float* __restrict__ pw2, half_t* __restrict__ Wt) {
    int m = blockIdx.x, nb = blockIdx.y * 16, kb = blockIdx.z * 16;
    const float* W = (m < 8) ? (bw1 + (size_t)m * DD * DD)
                  : (m < 16) ? (bw2 + (size_t)(m - 8) * DD * DD)
                             : pw2;
    __shared__ float s[16][17];
    int i = threadIdx.x >> 4, j = threadIdx.x & 15;
    s[i][j] = W[(size_t)(kb + i) * DD + nb + j];
    __syncthreads();
    Wt[(size_t)m * DD * DD + (size_t)(nb + i) * DD + kb + j] = (half_t)s[j][i];
}

// ---------------- CSR build (deterministic) ----------------
__global__ void csr_count_kernel(const float* __restrict__ adj, int* __restrict__ counts) {
    int i = blockIdx.x, tid = threadIdx.x;
    float c = 0.f;
    for (int j = tid; j < NTOT; j += 256) c += (adj[(size_t)i * NTOT + j] != 0.f) ? 1.f : 0.f;
    float t = blockReduceSum256(c);
    if (tid == 0) counts[i] = (int)(t + 0.5f);
}

__global__ void scan_kernel(const int* __restrict__ counts, int* __restrict__ row_ptr) {
    __shared__ int csum[256];
    int tid = threadIdx.x;
    int local[8]; int tot = 0;
    for (int u = 0; u < 8; ++u) { local[u] = counts[tid * 8 + u]; tot += local[u]; }
    csum[tid] = tot; __syncthreads();
    for (int off = 1; off < 256; off <<= 1) {
        int v = (tid >= off) ? csum[tid - off] : 0;
        __syncthreads();
        csum[tid] += v;
        __syncthreads();
    }
    int run = csum[tid] - tot;
    for (int u = 0; u < 8; ++u) { row_ptr[tid * 8 + u] = run; run += local[u]; }
    if (tid == 255) row_ptr[NTOT] = run;
}

__global__ void csr_fill_kernel(const float* __restrict__ adj, const int* __restrict__ row_ptr,
                                int* __restrict__ col) {
    int i = blockIdx.x, lane = threadIdx.x;  // 64 threads
    int base = row_ptr[i];
    int run = 0;
    for (int j0 = 0; j0 < NTOT; j0 += 64) {
        int j = j0 + lane;
        bool pred = adj[(size_t)i * NTOT + j] != 0.f;
        unsigned long long mask = __ballot(pred);
        if (pred) {
            int pos = run + __popcll(mask & ((1ull << lane) - 1ull));
            col[base + pos] = j;
        }
        run += __popcll(mask);
    }
}

// ---------------- maps / local neighbor lists ----------------
__global__ void init_maps_kernel(int* __restrict__ orig, int* __restrict__ inv) {
    int t = blockIdx.x * 256 + threadIdx.x;  // B*N
    int i = t & (NTOT - 1);
    orig[t] = i; inv[t] = i;  // tag 0
}

// level 0: local == global indices, replicate per batch
__global__ void build_lcol0_kernel(const int* __restrict__ row_ptr, const int* __restrict__ col,
                                   int* __restrict__ ldeg, int* __restrict__ lcol) {
    int t = blockIdx.x * 256 + threadIdx.x;  // B*NTOT
    int i = t & (NTOT - 1);
    int s = row_ptr[i], e = row_ptr[i + 1];
    int d = e - s; if (d > 64) d = 64;
    ldeg[t] = d;
    for (int p = 0; p < d; ++p) lcol[(size_t)t * 64 + p] = col[s + p];
}

// levels >=1: filter original CSR through inv-tag, emit local indices
__global__ void build_lcol_kernel(const int* __restrict__ row_ptr, const int* __restrict__ col,
                                  const int* __restrict__ orig, const int* __restrict__ inv,
                                  int* __restrict__ ldeg, int* __restrict__ lcol, int k, int tag) {
    int t = blockIdx.x * 256 + threadIdx.x;  // B*k
    int b = t / k, i = t - b * k;
    int key = b * NTOT + i;
    int o = orig[key];
    int s = row_ptr[o], e = row_ptr[o + 1];
    const int* invb = inv + b * NTOT;
    int cnt = 0;
    for (int p = s; p < e && cnt < 64; ++p) {
        int v = invb[col[p]];
        if ((v >> 12) == tag) { lcol[(size_t)key * 64 + cnt] = v & 4095; ++cnt; }
    }
    ldeg[key] = cnt;
}

// ---------------- fused layer kernel ----------------
// 32 rows/block, 256 threads (4 waves). Phases:
//   A: t = g*(eps1*z_s + sum_j z_j) + (eps1+deg)*b  -> LDS tb (f16)
//   B: mm1 (tb @ Wt1^T) + silu -> LDS ub (f16)
//   C: mm2 (ub @ Wt2^T) + residual h, row stats, z_out, optional pool score
template <int SCORE>
__global__ void __launch_bounds__(256) layer_kernel(
    float* __restrict__ h, const float* __restrict__ zin, float* __restrict__ zout,
    const half_t* __restrict__ Wt1, const half_t* __restrict__ Wt2,
    const float* __restrict__ b1v, const float* __restrict__ b2v,
    const float* __restrict__ gv, const float* __restrict__ bbv,
    const float* __restrict__ beps, int blk,
    const int* __restrict__ ldeg, const int* __restrict__ lcol,
    const float* __restrict__ poolp, const float* __restrict__ pinv_all,
    float* __restrict__ scores, int dep, int n) {
    __shared__ half_t tb[32][264];
    __shared__ half_t ub[32][264];
    __shared__ float part[4][32][3];
    __shared__ float mrs[32][2];
    int tid = threadIdx.x;
    int rowBase = blockIdx.x * 32;
    float eps1 = 1.0f + beps[blk];

    // ---- phase A: aggregation ----
    {
        int rl = tid >> 3, cg = tid & 7;       // 8 threads/row, 32 cols each
        int r = rowBase + rl;
        int b = r / n, i = r - b * n;
        const f32x4* zr = (const f32x4*)(zin + (size_t)r * DD) + cg * 8;
        f32x4 acc[8];
#pragma unroll
        for (int u = 0; u < 8; ++u) acc[u] = zr[u] * eps1;
        int key = b * NTOT + i;
        int deg = ldeg[key];
        const int* lc = lcol + (size_t)key * 64;
        const f32x4* zb = (const f32x4*)zin + (size_t)b * n * 64 + cg * 8;
        for (int p = 0; p < deg; ++p) {
            const f32x4* zj = zb + (size_t)lc[p] * 64;
#pragma unroll
            for (int u = 0; u < 8; ++u) acc[u] += zj[u];
        }
        float coefb = eps1 + (float)deg;
        const f32x4* g4 = (const f32x4*)gv + cg * 8;
        const f32x4* b4 = (const f32x4*)bbv + cg * 8;
#pragma unroll
        for (int u = 0; u < 8; ++u) {
            f32x4 tv = g4[u] * acc[u] + b4[u] * coefb;
            halfx4 th;
#pragma unroll
            for (int e = 0; e < 4; ++e) th[e] = (half_t)tv[e];
            *(halfx4*)&tb[rl][cg * 32 + u * 4] = th;
        }
    }
    __syncthreads();

    int w = tid >> 6, l = tid & 63;
    int lo = l & 15, hi = l >> 4;
    int kb = hi * 8;

    // ---- phase B: mm1 + silu -> ub ----
    {
        f32x4 acc[2][4] = {};
#pragma unroll
        for (int k0 = 0; k0 < DD; k0 += 32) {
            halfx8 a0 = *(const halfx8*)&tb[lo][kb + k0];
            halfx8 a1 = *(const halfx8*)&tb[16 + lo][kb + k0];
#pragma unroll
            for (int j = 0; j < 4; ++j) {
                halfx8 bj = *(const halfx8*)(Wt1 + (size_t)(w * 64 + j * 16 + lo) * DD + kb + k0);
                acc[0][j] = __builtin_amdgcn_mfma_f32_16x16x32_f16(a0, bj, acc[0][j], 0, 0, 0);
                acc[1][j] = __builtin_amdgcn_mfma_f32_16x16x32_f16(a1, bj, acc[1][j], 0, 0, 0);
            }
        }
        float bs[4];
#pragma unroll
        for (int j = 0; j < 4; ++j) bs[j] = b1v[w * 64 + j * 16 + lo];
#pragma unroll
        for (int i2 = 0; i2 < 2; ++i2)
#pragma unroll
            for (int q = 0; q < 4; ++q)
#pragma unroll
                for (int j = 0; j < 4; ++j) {
                    float v = acc[i2][j][q] + bs[j];
                    v = v / (1.0f + expf(-v));
                    ub[i2 * 16 + hi * 4 + q][w * 64 + j * 16 + lo] = (half_t)v;
                }
    }
    __syncthreads();

    // ---- phase C: mm2 + residual + stats (+score) + z ----
    {
        f32x4 acc[2][4] = {};
#pragma unroll
        for (int k0 = 0; k0 < DD; k0 += 32) {
            halfx8 a0 = *(const halfx8*)&ub[lo][kb + k0];
            halfx8 a1 = *(const halfx8*)&ub[16 + lo][kb + k0];
#pragma unroll
            for (int j = 0; j < 4; ++j) {
                halfx8 bj = *(const halfx8*)(Wt2 + (size_t)(w * 64 + j * 16 + lo) * DD + kb + k0);
                acc[0][j] = __builtin_amdgcn_mfma_f32_16x16x32_f16(a0, bj, acc[0][j], 0, 0, 0);
                acc[1][j] = __builtin_amdgcn_mfma_f32_16x16x32_f16(a1, bj, acc[1][j], 0, 0, 0);
            }
        }
        float bs[4], pv[4] = {};
#pragma unroll
        for (int j = 0; j < 4; ++j) bs[j] = b2v[w * 64 + j * 16 + lo];
        if (SCORE) {
#pragma unroll
            for (int j = 0; j < 4; ++j) pv[j] = poolp[dep * DD + w * 64 + j * 16 + lo];
        }
        float vh[2][4][4];
#pragma unroll
        for (int i2 = 0; i2 < 2; ++i2)
#pragma unroll
            for (int q = 0; q < 4; ++q) {
                int r = rowBase + i2 * 16 + hi * 4 + q;
                float s = 0.f, ss = 0.f, sp = 0.f;
#pragma unroll
                for (int j = 0; j < 4; ++j) {
                    int c = w * 64 + j * 16 + lo;
                    float v = h[(size_t)r * DD + c] + acc[i2][j][q] + bs[j];
                    vh[i2][j][q] = v;
                    s += v; ss += v * v;
                    if (SCORE) sp += v * pv[j];
                }
#pragma unroll
                for (int m = 1; m < 16; m <<= 1) {
                    s += __shfl_xor(s, m); ss += __shfl_xor(ss, m);
                    if (SCORE) sp += __shfl_xor(sp, m);
                }
                if (lo == 0) {
                    int rl = i2 * 16 + hi * 4 + q;
                    part[w][rl][0] = s; part[w][rl][1] = ss;
                    if (SCORE) part[w][rl][2] = sp;
                }
            }
        __syncthreads();
        if (tid < 32) {
            float s = 0.f, ss = 0.f, sp = 0.f;
#pragma unroll
            for (int w2 = 0; w2 < 4; ++w2) {
                s += part[w2][tid][0]; ss += part[w2][tid][1];
                if (SCORE) sp += part[w2][tid][2];
            }
            float mean = s * (1.0f / DD);
            float var = ss * (1.0f / DD) - mean * mean;
            mrs[tid][0] = mean;
            mrs[tid][1] = rsqrtf(var + 1e-5f);
            if (SCORE) {
                int r = rowBase + tid;
                int b2 = r / n, ii = r - b2 * n;
                scores[b2 * NTOT + ii] = sp * pinv_all[dep];
            }
        }
        __syncthreads();
#pragma unroll
        for (int i2 = 0; i2 < 2; ++i2)
#pragma unroll
            for (int q = 0; q < 4; ++q) {
                int rl = i2 * 16 + hi * 4 + q;
                int r = rowBase + rl;
                float mean = mrs[rl][0], rs = mrs[rl][1];
#pragma unroll
                for (int j = 0; j < 4; ++j) {
                    int c = w * 64 + j * 16 + lo;
                    float v = vh[i2][j][q];
                    h[(size_t)r * DD + c] = v;
                    zout[(size_t)r * DD + c] = (v - mean) * rs;
                }
            }
    }
}

// ---------------- standalone mm for positional embedding ----------------
__global__ void __launch_bounds__(256) mm_pe_kernel(const half_t* __restrict__ A,
                                                    const half_t* __restrict__ Wt,
                                                    const float* __restrict__ bias,
                                                    float* __restrict__ C) {
    int tid = threadIdx.x;
    int w = tid >> 6, l = tid & 63;
    int lo = l & 15, hi = l >> 4;
    int rowBase = blockIdx.x * 32;
    int kb = hi * 8;
    const half_t* a0p = A + (size_t)(rowBase + lo) * DD + kb;
    const half_t* a1p = a0p + 16 * DD;
    f32x4 acc[2][4] = {};
#pragma unroll
    for (int k0 = 0; k0 < DD; k0 += 32) {
        halfx8 a0 = *(const halfx8*)(a0p + k0);
        halfx8 a1 = *(const halfx8*)(a1p + k0);
#pragma unroll
        for (int j = 0; j < 4; ++j) {
            halfx8 bj = *(const halfx8*)(Wt + (size_t)(w * 64 + j * 16 + lo) * DD + kb + k0);
            acc[0][j] = __builtin_amdgcn_mfma_f32_16x16x32_f16(a0, bj, acc[0][j], 0, 0, 0);
            acc[1][j] = __builtin_amdgcn_mfma_f32_16x16x32_f16(a1, bj, acc[1][j], 0, 0, 0);
        }
    }
#pragma unroll
    for (int i2 = 0; i2 < 2; ++i2)
#pragma unroll
        for (int q = 0; q < 4; ++q)
#pragma unroll
            for (int j = 0; j < 4; ++j) {
                int r = rowBase + i2 * 16 + hi * 4 + q;
                int c = w * 64 + j * 16 + lo;
                C[(size_t)r * DD + c] = acc[i2][j][q] + bias[c];
            }
}

// ---------------- pooling ----------------
// radix-select threshold (k-th largest) + tie-aware stable compaction
__global__ void topk_kernel(const float* __restrict__ scores, const int* __restrict__ orig_cur,
                            int* __restrict__ orig_next, int* __restrict__ idx_local,
                            float* __restrict__ gate, int n, int k) {
    __shared__ unsigned keys[2048];
    __shared__ int hist[256];
    __shared__ int sg[256], se[256];
    __shared__ int sh_bucket, sh_r;
    int b = blockIdx.x;
    const float* sc = scores + b * NTOT;
    int tid = threadIdx.x;
    for (int i = tid; i < n; i += 256) {
        unsigned u = __float_as_uint(sc[i]);
        keys[i] = (u & 0x80000000u) ? ~u : (u | 0x80000000u);
    }
    if (tid == 0) sh_r = n - k;
    __syncthreads();
    unsigned prefix = 0;
    for (int shift = 24; shift >= 0; shift -= 8) {
        hist[tid] = 0;
        __syncthreads();
        unsigned mask = (shift == 24) ? 0u : (0xFFFFFFFFu << (shift + 8));
        for (int i = tid; i < n; i += 256) {
            unsigned key = keys[i];
            if ((key & mask) == (prefix & mask))
                atomicAdd(&hist[(key >> shift) & 255], 1);
        }
        __syncthreads();
        int cnt = hist[tid];
        sg[tid] = cnt;
        __syncthreads();
        for (int off = 1; off < 256; off <<= 1) {
            int v = (tid >= off) ? sg[tid - off] : 0;
            __syncthreads();
            sg[tid] += v;
            __syncthreads();
        }
        int incl = sg[tid], excl = incl - cnt;
        int r = sh_r;
        if (excl <= r && r < incl) { sh_bucket = tid; sh_r = r - excl; }
        __syncthreads();
        prefix |= ((unsigned)sh_bucket) << shift;
        __syncthreads();
    }
    unsigned uthr = (prefix & 0x80000000u) ? (prefix ^ 0x80000000u) : ~prefix;
    float thr = __uint_as_float(uthr);
    int chunk = n / 256;
    int base = tid * chunk;
    int cgt = 0, ceq = 0;
    for (int u = 0; u < chunk; ++u) {
        float s = sc[base + u];
        cgt += (s > thr); ceq += (s == thr);
    }
    sg[tid] = cgt; se[tid] = ceq; __syncthreads();
    for (int off = 1; off < 256; off <<= 1) {
        int vg = (tid >= off) ? sg[tid - off] : 0;
        int ve = (tid >= off) ? se[tid - off] : 0;
        __syncthreads();
        sg[tid] += vg; se[tid] += ve;
        __syncthreads();
    }
    int total_gt = sg[255];
    int ties = k - total_gt;
    int gtb = sg[tid] - cgt, eqb = se[tid] - ceq;
    for (int u = 0; u < chunk; ++u) {
        int i = base + u;
        float s = sc[i];
        bool isgt = (s > thr), iseq = (s == thr);
        bool keep = isgt || (iseq && eqb < ties);
        if (keep) {
            int pos = gtb + (eqb < ties ? eqb : ties);
            idx_local[b * NTOT + pos] = i;
            gate[b * NTOT + pos] = tanhf(s);
            orig_next[b * NTOT + pos] = orig_cur[b * NTOT + i];
        }
        gtb += isgt; eqb += iseq;
    }
}

// gather gated rows, recompute stats, write z, and set inverse map
__global__ void __launch_bounds__(64) gather_kernel(
    const float* __restrict__ h, const int* __restrict__ idx_local,
    const float* __restrict__ gate, const int* __restrict__ orig_new,
    float* __restrict__ hout, float* __restrict__ zout, int* __restrict__ inv,
    int n_old, int k, int tag) {
    int r = blockIdx.x;  // B*k
    int b = r / k, rr = r - b * k;
    int lane = threadIdx.x;
    int src = idx_local[b * NTOT + rr];
    float gg = gate[b * NTOT + rr];
    f32x4 v = ((const f32x4*)h)[(size_t)(b * n_old + src) * 64 + lane] * gg;
    ((f32x4*)hout)[(size_t)r * 64 + lane] = v;
    float s = v[0] + v[1] + v[2] + v[3];
    float ss = v[0] * v[0] + v[1] * v[1] + v[2] * v[2] + v[3] * v[3];
#pragma unroll
    for (int m = 1; m < 64; m <<= 1) { s += __shfl_xor(s, m); ss += __shfl_xor(ss, m); }
    float mean = s * (1.0f / DD);
    float rs = rsqrtf(ss * (1.0f / DD) - mean * mean + 1e-5f);
    f32x4 zv = (v - mean) * rs;
    ((f32x4*)zout)[(size_t)r * 64 + lane] = zv;
    if (lane == 0) inv[b * NTOT + orig_new[b * NTOT + rr]] = (tag << 12) | rr;
}

// ---------------- readout ----------------
__global__ void readout_kernel(const float* __restrict__ h, float* __restrict__ feat) {
    int bd = blockIdx.x;  // B*256
    int b = bd >> 8, d = bd & 255;
    int i = threadIdx.x;
    float x = h[(size_t)(b * 256 + i) * DD + d];
    float m = blockReduceSum256(x) / 256.0f;
    float diff = x - m;
    float s2 = blockReduceSum256(diff * diff);
    if (i == 0) {
        feat[b * 512 + d] = m;
        feat[b * 512 + 256 + d] = sqrtf(s2 / 255.0f) + 1e-6f;
    }
}

__global__ void final_kernel(const float* __restrict__ feat, const float* __restrict__ lw,
                             const float* __restrict__ lb, float* __restrict__ out) {
    int b = blockIdx.x, l = threadIdx.x;  // 128 threads
    float acc = lb[l];
    const float* f = feat + b * 512;
    for (int k = 0; k < 512; ++k) acc += f[k] * lw[k * 128 + l];
    out[b * 128 + l] = acc;
}

extern "C" void kernel_launch(void* const* d_in, const int* in_sizes, int n_in,
                              void* d_out, int out_size, void* d_ws, size_t ws_size,
                              hipStream_t stream) {
    (void)in_sizes; (void)n_in; (void)out_size; (void)ws_size;
    const float* x     = (const float*)d_in[0];
    const float* adj   = (const float*)d_in[1];
    const float* pos   = (const float*)d_in[2];
    const float* in_w  = (const float*)d_in[3];
    const float* in_b  = (const float*)d_in[4];
    const float* pw1   = (const float*)d_in[5];
    const float* pb1   = (const float*)d_in[6];
    const float* pw2   = (const float*)d_in[7];
    const float* pb2   = (const float*)d_in[8];
    const float* bg    = (const float*)d_in[9];
    const float* bb    = (const float*)d_in[10];
    const float* bw1   = (const float*)d_in[11];
    const float* bb1   = (const float*)d_in[12];
    const float* bw2   = (const float*)d_in[13];
    const float* bb2   = (const float*)d_in[14];
    const float* beps  = (const float*)d_in[15];
    const float* poolp = (const float*)d_in[16];
    const float* lw    = (const float*)d_in[17];
    const float* lb    = (const float*)d_in[18];
    float* out = (float*)d_out;

    char* wp = (char*)d_ws;
    auto alloc = [&](size_t bytes) -> void* {
        void* p = (void*)wp;
        wp += (bytes + 255) & ~(size_t)255;
        return p;
    };
    const size_t HBYTES = (size_t)BSZ * NTOT * DD * sizeof(float);  // 8.39 MB
    float*  h    = (float*)alloc(HBYTES);
    float*  bufC = (float*)alloc(HBYTES);          // pe out / gather target
    float*  zA   = (float*)alloc(HBYTES);
    float*  zB   = (float*)alloc(HBYTES);
    half_t* tbq  = (half_t*)alloc((size_t)NTOT * DD * sizeof(half_t));
    half_t* Wt   = (half_t*)alloc((size_t)17 * DD * DD * sizeof(half_t));
    float* pstats  = (float*)alloc(8 * sizeof(float));
    float* pinv    = (float*)alloc(4 * sizeof(float));
    float* scores  = (float*)alloc(BSZ * NTOT * sizeof(float));
    float* gate    = (float*)alloc(BSZ * NTOT * sizeof(float));
    int*   origA   = (int*)alloc(BSZ * NTOT * sizeof(int));
    int*   origB   = (int*)alloc(BSZ * NTOT * sizeof(int));
    int*   idxl    = (int*)alloc(BSZ * NTOT * sizeof(int));
    int*   inv     = (int*)alloc(BSZ * NTOT * sizeof(int));
    int*   counts  = (int*)alloc(NTOT * sizeof(int));
    int*   row_ptr = (int*)alloc((NTOT + 1) * sizeof(int));
    int*   col     = (int*)alloc((size_t)NTOT * 64 * sizeof(int));
    int*   ldeg    = (int*)alloc(BSZ * NTOT * sizeof(int));
    int*   lcol    = (int*)alloc((size_t)BSZ * NTOT * 64 * sizeof(int));
    float* feat    = (float*)alloc(BSZ * 512 * sizeof(float));

    // ---- init ----
    wprep_kernel<<<dim3(17, 16, 16), 256, 0, stream>>>(bw1, bw2, pw2, Wt);
    pnorm_kernel<<<3, 256, 0, stream>>>(poolp, pinv);
    pos_stats_kernel<<<1, 256, 0, stream>>>(pos, pstats);
    pe_q_kernel<<<NTOT, 256, 0, stream>>>(pos, pstats, pw1, pb1, tbq);
    mm_pe_kernel<<<NTOT / 32, 256, 0, stream>>>(tbq, Wt + (size_t)16 * DD * DD, pb2, bufC);
    init_h_kernel<<<BSZ * NTOT, 256, 0, stream>>>(x, in_w, in_b, bufC, h, zA);
    csr_count_kernel<<<NTOT, 256, 0, stream>>>(adj, counts);
    scan_kernel<<<1, 256, 0, stream>>>(counts, row_ptr);
    csr_fill_kernel<<<NTOT, 64, 0, stream>>>(adj, row_ptr, col);
    init_maps_kernel<<<(BSZ * NTOT) / 256, 256, 0, stream>>>(origA, inv);
    build_lcol0_kernel<<<(BSZ * NTOT) / 256, 256, 0, stream>>>(row_ptr, col, ldeg, lcol);

    float* hcur = h;
    float* halt = bufC;
    float* zin = zA;
    float* zout = zB;
    int* orig = origA;
    int* orign = origB;
    int n = NTOT;
    int blk = 0;
    for (int dep = 0; dep < 4; ++dep) {
        for (int s = 0; s < 2; ++s) {
            int rows = BSZ * n;
            if (s == 1 && dep < 3) {
                layer_kernel<1><<<rows / 32, 256, 0, stream>>>(
                    hcur, zin, zout, Wt + (size_t)blk * DD * DD, Wt + (size_t)(8 + blk) * DD * DD,
                    bb1 + blk * DD, bb2 + blk * DD, bg + blk * DD, bb + blk * DD,
                    beps, blk, ldeg, lcol, poolp, pinv, scores, dep, n);
            } else {
                layer_kernel<0><<<rows / 32, 256, 0, stream>>>(
                    hcur, zin, zout, Wt + (size_t)blk * DD * DD, Wt + (size_t)(8 + blk) * DD * DD,
                    bb1 + blk * DD, bb2 + blk * DD, bg + blk * DD, bb + blk * DD,
                    beps, blk, ldeg, lcol, nullptr, nullptr, nullptr, 0, n);
            }
            { float* t = zin; zin = zout; zout = t; }
            ++blk;
        }
        if (dep < 3) {
            int k = n / 2;
            topk_kernel<<<BSZ, 256, 0, stream>>>(scores, orig, orign, idxl, gate, n, k);
            { int* t = orig; orig = orign; orign = t; }
            gather_kernel<<<BSZ * k, 64, 0, stream>>>(hcur, idxl, gate, orig, halt, zin, inv,
                                                      n, k, dep + 1);
            { float* t = hcur; hcur = halt; halt = t; }
            build_lcol_kernel<<<(BSZ * k) / 256, 256, 0, stream>>>(row_ptr, col, orig, inv,
                                                                   ldeg, lcol, k, dep + 1);
            n = k;
        }
    }
    // ---- readout ----
    readout_kernel<<<BSZ * 256, 256, 0, stream>>>(hcur, feat);
    final_kernel<<<BSZ, 128, 0, stream>>>(feat, lw, lb, out);
}

// Round 5
// 362.419 us; speedup vs baseline: 1.0680x; 1.0620x over previous
//
#include <hip/hip_runtime.h>
#include <hip/hip_bf16.h>

#define NTOT 2048
#define DD 256
#define BSZ 4

typedef _Float16 half_t;
typedef __attribute__((ext_vector_type(8))) _Float16 halfx8;
typedef __attribute__((ext_vector_type(4))) _Float16 halfx4;
typedef __attribute__((ext_vector_type(4))) float f32x4;

// ---------------- block reduce (256 threads) ----------------
__device__ __forceinline__ float blockReduceSum256(float v) {
    __shared__ float red[4];
    for (int off = 32; off > 0; off >>= 1) v += __shfl_down(v, off);
    int lane = threadIdx.x & 63, w = threadIdx.x >> 6;
    __syncthreads();
    if (lane == 0) red[w] = v;
    __syncthreads();
    return red[0] + red[1] + red[2] + red[3];
}

// ---------------- pos stats ----------------
__global__ void pos_stats_kernel(const float* __restrict__ pos, float* __restrict__ stats) {
    int tid = threadIdx.x;
    float s[3] = {0.f, 0.f, 0.f};
    for (int i = tid; i < NTOT; i += 256)
        for (int c = 0; c < 3; ++c) s[c] += pos[i * 3 + c];
    float m[3];
    for (int c = 0; c < 3; ++c) m[c] = blockReduceSum256(s[c]) / (float)NTOT;
    float q[3] = {0.f, 0.f, 0.f};
    for (int i = tid; i < NTOT; i += 256)
        for (int c = 0; c < 3; ++c) { float d = pos[i * 3 + c] - m[c]; q[c] += d * d; }
    for (int c = 0; c < 3; ++c) {
        float t = blockReduceSum256(q[c]);
        if (tid == 0) {
            float var = ((float)BSZ * t) / ((float)BSZ * NTOT - 1.0f);
            stats[c] = m[c];
            stats[3 + c] = 1.0f / (sqrtf(var) + 1e-8f);
        }
    }
}

__global__ void pnorm_kernel(const float* __restrict__ poolp, float* __restrict__ pinv) {
    int dep = blockIdx.x, tid = threadIdx.x;
    float v = poolp[dep * DD + tid];
    float ss = blockReduceSum256(v * v);
    if (tid == 0) pinv[dep] = rsqrtf(ss);
}

// q[i,d] = silu(pn@pw1 + pb1) -> f16
__global__ void pe_q_kernel(const float* __restrict__ pos, const float* __restrict__ stats,
                            const float* __restrict__ pw1, const float* __restrict__ pb1,
                            half_t* __restrict__ q) {
    int i = blockIdx.x, d = threadIdx.x;
    float acc = pb1[d];
    for (int c = 0; c < 3; ++c) {
        float pn = (pos[i * 3 + c] - stats[c]) * stats[3 + c];
        acc += pn * pw1[c * DD + d];
    }
    acc = acc / (1.0f + expf(-acc));
    q[i * DD + d] = (half_t)acc;
}

// h = x@in_w + in_b + pe; also write z = (h-m)*rstd
__global__ void init_h_kernel(const float* __restrict__ x, const float* __restrict__ in_w,
                              const float* __restrict__ in_b, const float* __restrict__ pe,
                              float* __restrict__ h, float* __restrict__ z) {
    int row = blockIdx.x, d = threadIdx.x;
    float acc = in_b[d];
    for (int k = 0; k < 16; ++k) acc += x[row * 16 + k] * in_w[k * DD + d];
    float v = acc + pe[(row & (NTOT - 1)) * DD + d];
    h[(size_t)row * DD + d] = v;
    float s = blockReduceSum256(v);
    float ss = blockReduceSum256(v * v);
    float mean = s * (1.0f / DD);
    float rs = rsqrtf(ss * (1.0f / DD) - mean * mean + 1e-5f);
    z[(size_t)row * DD + d] = (v - mean) * rs;
}

// ---------------- weight prep: Wt[m][n][k] = f16(W_m[k][n]) ----------------
__global__ void wprep_kernel(const float* __restrict__ bw1, const float* __restrict__ bw2,
                             const float* __restrict__ pw2, half_t* __restrict__ Wt) {
    int m = blockIdx.x, nb = blockIdx.y * 16, kb = blockIdx.z * 16;
    const float* W = (m < 8) ? (bw1 + (size_t)m * DD * DD)
                  : (m < 16) ? (bw2 + (size_t)(m - 8) * DD * DD)
                             : pw2;
    __shared__ float s[16][17];
    int i = threadIdx.x >> 4, j = threadIdx.x & 15;
    s[i][j] = W[(size_t)(kb + i) * DD + nb + j];
    __syncthreads();
    Wt[(size_t)m * DD * DD + (size_t)(nb + i) * DD + kb + j] = (half_t)s[j][i];
}

// ---------------- CSR build (deterministic) ----------------
__global__ void csr_count_kernel(const float* __restrict__ adj, int* __restrict__ counts) {
    int i = blockIdx.x, tid = threadIdx.x;
    float c = 0.f;
    for (int j = tid; j < NTOT; j += 256) c += (adj[(size_t)i * NTOT + j] != 0.f) ? 1.f : 0.f;
    float t = blockReduceSum256(c);
    if (tid == 0) counts[i] = (int)(t + 0.5f);
}

__global__ void scan_kernel(const int* __restrict__ counts, int* __restrict__ row_ptr) {
    __shared__ int csum[256];
    int tid = threadIdx.x;
    int local[8]; int tot = 0;
    for (int u = 0; u < 8; ++u) { local[u] = counts[tid * 8 + u]; tot += local[u]; }
    csum[tid] = tot; __syncthreads();
    for (int off = 1; off < 256; off <<= 1) {
        int v = (tid >= off) ? csum[tid - off] : 0;
        __syncthreads();
        csum[tid] += v;
        __syncthreads();
    }
    int run = csum[tid] - tot;
    for (int u = 0; u < 8; ++u) { row_ptr[tid * 8 + u] = run; run += local[u]; }
    if (tid == 255) row_ptr[NTOT] = run;
}

__global__ void csr_fill_kernel(const float* __restrict__ adj, const int* __restrict__ row_ptr,
                                int* __restrict__ col) {
    int i = blockIdx.x, lane = threadIdx.x;  // 64 threads
    int base = row_ptr[i];
    int run = 0;
    for (int j0 = 0; j0 < NTOT; j0 += 64) {
        int j = j0 + lane;
        bool pred = adj[(size_t)i * NTOT + j] != 0.f;
        unsigned long long mask = __ballot(pred);
        if (pred) {
            int pos = run + __popcll(mask & ((1ull << lane) - 1ull));
            col[base + pos] = j;
        }
        run += __popcll(mask);
    }
}

// ---------------- maps / local neighbor lists ----------------
__global__ void init_maps_kernel(int* __restrict__ orig, int* __restrict__ inv) {
    int t = blockIdx.x * 256 + threadIdx.x;  // B*N
    int i = t & (NTOT - 1);
    orig[t] = i; inv[t] = i;  // tag 0
}

__global__ void build_lcol0_kernel(const int* __restrict__ row_ptr, const int* __restrict__ col,
                                   int* __restrict__ ldeg, int* __restrict__ lcol) {
    int t = blockIdx.x * 256 + threadIdx.x;  // B*NTOT
    int i = t & (NTOT - 1);
    int s = row_ptr[i], e = row_ptr[i + 1];
    int d = e - s; if (d > 64) d = 64;
    ldeg[t] = d;
    for (int p = 0; p < d; ++p) lcol[(size_t)t * 64 + p] = col[s + p];
}

__global__ void build_lcol_kernel(const int* __restrict__ row_ptr, const int* __restrict__ col,
                                  const int* __restrict__ orig, const int* __restrict__ inv,
                                  int* __restrict__ ldeg, int* __restrict__ lcol, int k, int tag) {
    int t = blockIdx.x * 256 + threadIdx.x;  // B*k
    int b = t / k, i = t - b * k;
    int key = b * NTOT + i;
    int o = orig[key];
    int s = row_ptr[o], e = row_ptr[o + 1];
    const int* invb = inv + b * NTOT;
    int cnt = 0;
    for (int p = s; p < e && cnt < 64; ++p) {
        int v = invb[col[p]];
        if ((v >> 12) == tag) { lcol[(size_t)key * 64 + cnt] = v & 4095; ++cnt; }
    }
    ldeg[key] = cnt;
}

// ---------------- standalone aggregation: one wave per row ----------------
// t = g*(eps1*z_s + sum_j z_j) + (eps1+deg)*b  -> f16 tb
__global__ void __launch_bounds__(256) agg_kernel(
    const float* __restrict__ zin, half_t* __restrict__ tb,
    const float* __restrict__ gv, const float* __restrict__ bbv,
    const float* __restrict__ beps, int blk,
    const int* __restrict__ ldeg, const int* __restrict__ lcol, int n) {
    int w = threadIdx.x >> 6, lane = threadIdx.x & 63;
    int r = blockIdx.x * 4 + w;  // 0..B*n-1
    int b = r / n, i = r - b * n;
    float eps1 = 1.0f + beps[blk];
    const f32x4* zb = (const f32x4*)zin + (size_t)b * n * 64;
    f32x4 acc = zb[(size_t)i * 64 + lane] * eps1;
    int key = b * NTOT + i;
    int deg = ldeg[key];
    const int* lc = lcol + (size_t)key * 64;
    for (int p = 0; p < deg; ++p)
        acc += zb[(size_t)lc[p] * 64 + lane];
    float coefb = eps1 + (float)deg;
    f32x4 gvv = ((const f32x4*)gv)[lane];
    f32x4 bvv = ((const f32x4*)bbv)[lane];
    f32x4 tv = gvv * acc + bvv * coefb;
    halfx4 th;
#pragma unroll
    for (int e = 0; e < 4; ++e) th[e] = (half_t)tv[e];
    ((halfx4*)tb)[(size_t)r * 64 + lane] = th;
}

// ---------------- fused MLP: mm1+silu -> LDS ub -> mm2 + residual/stats/z (+score) ----------------
// 32 rows/block, 256 thr (4 waves, wave w -> cols [64w,64w+64)). A read from global tb.
template <int SCORE>
__global__ void __launch_bounds__(256) mlp_kernel(
    float* __restrict__ h, const half_t* __restrict__ tb, float* __restrict__ zout,
    const half_t* __restrict__ Wt1, const half_t* __restrict__ Wt2,
    const float* __restrict__ b1v, const float* __restrict__ b2v,
    const float* __restrict__ poolp, const float* __restrict__ pinv_all,
    float* __restrict__ scores, int dep, int n) {
    __shared__ half_t ub[32][264];
    __shared__ float part[4][32][3];
    __shared__ float mrs[32][2];
    int tid = threadIdx.x;
    int rowBase = blockIdx.x * 32;
    int w = tid >> 6, l = tid & 63;
    int lo = l & 15, hi = l >> 4;
    int kb = hi * 8;

    // ---- mm1 + silu -> ub ----
    {
        const half_t* a0p = tb + (size_t)(rowBase + lo) * DD + kb;
        const half_t* a1p = a0p + 16 * DD;
        f32x4 acc[2][4] = {};
#pragma unroll
        for (int k0 = 0; k0 < DD; k0 += 32) {
            halfx8 a0 = *(const halfx8*)(a0p + k0);
            halfx8 a1 = *(const halfx8*)(a1p + k0);
#pragma unroll
            for (int j = 0; j < 4; ++j) {
                halfx8 bj = *(const halfx8*)(Wt1 + (size_t)(w * 64 + j * 16 + lo) * DD + kb + k0);
                acc[0][j] = __builtin_amdgcn_mfma_f32_16x16x32_f16(a0, bj, acc[0][j], 0, 0, 0);
                acc[1][j] = __builtin_amdgcn_mfma_f32_16x16x32_f16(a1, bj, acc[1][j], 0, 0, 0);
            }
        }
        float bs[4];
#pragma unroll
        for (int j = 0; j < 4; ++j) bs[j] = b1v[w * 64 + j * 16 + lo];
#pragma unroll
        for (int i2 = 0; i2 < 2; ++i2)
#pragma unroll
            for (int q = 0; q < 4; ++q)
#pragma unroll
                for (int j = 0; j < 4; ++j) {
                    float v = acc[i2][j][q] + bs[j];
                    v = v / (1.0f + expf(-v));
                    ub[i2 * 16 + hi * 4 + q][w * 64 + j * 16 + lo] = (half_t)v;
                }
    }
    __syncthreads();

    // ---- mm2 + residual + stats (+score) + z ----
    {
        f32x4 acc[2][4] = {};
#pragma unroll
        for (int k0 = 0; k0 < DD; k0 += 32) {
            halfx8 a0 = *(const halfx8*)&ub[lo][kb + k0];
            halfx8 a1 = *(const halfx8*)&ub[16 + lo][kb + k0];
#pragma unroll
            for (int j = 0; j < 4; ++j) {
                halfx8 bj = *(const halfx8*)(Wt2 + (size_t)(w * 64 + j * 16 + lo) * DD + kb + k0);
                acc[0][j] = __builtin_amdgcn_mfma_f32_16x16x32_f16(a0, bj, acc[0][j], 0, 0, 0);
                acc[1][j] = __builtin_amdgcn_mfma_f32_16x16x32_f16(a1, bj, acc[1][j], 0, 0, 0);
            }
        }
        float bs[4], pv[4] = {};
#pragma unroll
        for (int j = 0; j < 4; ++j) bs[j] = b2v[w * 64 + j * 16 + lo];
        if (SCORE) {
#pragma unroll
            for (int j = 0; j < 4; ++j) pv[j] = poolp[dep * DD + w * 64 + j * 16 + lo];
        }
        float vh[2][4][4];
#pragma unroll
        for (int i2 = 0; i2 < 2; ++i2)
#pragma unroll
            for (int q = 0; q < 4; ++q) {
                int r = rowBase + i2 * 16 + hi * 4 + q;
                float s = 0.f, ss = 0.f, sp = 0.f;
#pragma unroll
                for (int j = 0; j < 4; ++j) {
                    int c = w * 64 + j * 16 + lo;
                    float v = h[(size_t)r * DD + c] + acc[i2][j][q] + bs[j];
                    vh[i2][j][q] = v;
                    s += v; ss += v * v;
                    if (SCORE) sp += v * pv[j];
                }
#pragma unroll
                for (int m = 1; m < 16; m <<= 1) {
                    s += __shfl_xor(s, m); ss += __shfl_xor(ss, m);
                    if (SCORE) sp += __shfl_xor(sp, m);
                }
                if (lo == 0) {
                    int rl = i2 * 16 + hi * 4 + q;
                    part[w][rl][0] = s; part[w][rl][1] = ss;
                    if (SCORE) part[w][rl][2] = sp;
                }
            }
        __syncthreads();
        if (tid < 32) {
            float s = 0.f, ss = 0.f, sp = 0.f;
#pragma unroll
            for (int w2 = 0; w2 < 4; ++w2) {
                s += part[w2][tid][0]; ss += part[w2][tid][1];
                if (SCORE) sp += part[w2][tid][2];
            }
            float mean = s * (1.0f / DD);
            float var = ss * (1.0f / DD) - mean * mean;
            mrs[tid][0] = mean;
            mrs[tid][1] = rsqrtf(var + 1e-5f);
            if (SCORE) {
                int r = rowBase + tid;
                int b2 = r / n, ii = r - b2 * n;
                scores[b2 * NTOT + ii] = sp * pinv_all[dep];
            }
        }
        __syncthreads();
#pragma unroll
        for (int i2 = 0; i2 < 2; ++i2)
#pragma unroll
            for (int q = 0; q < 4; ++q) {
                int rl = i2 * 16 + hi * 4 + q;
                int r = rowBase + rl;
                float mean = mrs[rl][0], rs = mrs[rl][1];
#pragma unroll
                for (int j = 0; j < 4; ++j) {
                    int c = w * 64 + j * 16 + lo;
                    float v = vh[i2][j][q];
                    h[(size_t)r * DD + c] = v;
                    zout[(size_t)r * DD + c] = (v - mean) * rs;
                }
            }
    }
}

// ---------------- standalone mm for positional embedding ----------------
__global__ void __launch_bounds__(256) mm_pe_kernel(const half_t* __restrict__ A,
                                                    const half_t* __restrict__ Wt,
                                                    const float* __restrict__ bias,
                                                    float* __restrict__ C) {
    int tid = threadIdx.x;
    int w = tid >> 6, l = tid & 63;
    int lo = l & 15, hi = l >> 4;
    int rowBase = blockIdx.x * 32;
    int kb = hi * 8;
    const half_t* a0p = A + (size_t)(rowBase + lo) * DD + kb;
    const half_t* a1p = a0p + 16 * DD;
    f32x4 acc[2][4] = {};
#pragma unroll
    for (int k0 = 0; k0 < DD; k0 += 32) {
        halfx8 a0 = *(const halfx8*)(a0p + k0);
        halfx8 a1 = *(const halfx8*)(a1p + k0);
#pragma unroll
        for (int j = 0; j < 4; ++j) {
            halfx8 bj = *(const halfx8*)(Wt + (size_t)(w * 64 + j * 16 + lo) * DD + kb + k0);
            acc[0][j] = __builtin_amdgcn_mfma_f32_16x16x32_f16(a0, bj, acc[0][j], 0, 0, 0);
            acc[1][j] = __builtin_amdgcn_mfma_f32_16x16x32_f16(a1, bj, acc[1][j], 0, 0, 0);
        }
    }
#pragma unroll
    for (int i2 = 0; i2 < 2; ++i2)
#pragma unroll
        for (int q = 0; q < 4; ++q)
#pragma unroll
            for (int j = 0; j < 4; ++j) {
                int r = rowBase + i2 * 16 + hi * 4 + q;
                int c = w * 64 + j * 16 + lo;
                C[(size_t)r * DD + c] = acc[i2][j][q] + bias[c];
            }
}

// ---------------- pooling ----------------
__global__ void topk_kernel(const float* __restrict__ scores, const int* __restrict__ orig_cur,
                            int* __restrict__ orig_next, int* __restrict__ idx_local,
                            float* __restrict__ gate, int n, int k) {
    __shared__ unsigned keys[2048];
    __shared__ int hist[256];
    __shared__ int sg[256], se[256];
    __shared__ int sh_bucket, sh_r;
    int b = blockIdx.x;
    const float* sc = scores + b * NTOT;
    int tid = threadIdx.x;
    for (int i = tid; i < n; i += 256) {
        unsigned u = __float_as_uint(sc[i]);
        keys[i] = (u & 0x80000000u) ? ~u : (u | 0x80000000u);
    }
    if (tid == 0) sh_r = n - k;
    __syncthreads();
    unsigned prefix = 0;
    for (int shift = 24; shift >= 0; shift -= 8) {
        hist[tid] = 0;
        __syncthreads();
        unsigned mask = (shift == 24) ? 0u : (0xFFFFFFFFu << (shift + 8));
        for (int i = tid; i < n; i += 256) {
            unsigned key = keys[i];
            if ((key & mask) == (prefix & mask))
                atomicAdd(&hist[(key >> shift) & 255], 1);
        }
        __syncthreads();
        int cnt = hist[tid];
        sg[tid] = cnt;
        __syncthreads();
        for (int off = 1; off < 256; off <<= 1) {
            int v = (tid >= off) ? sg[tid - off] : 0;
            __syncthreads();
            sg[tid] += v;
            __syncthreads();
        }
        int incl = sg[tid], excl = incl - cnt;
        int r = sh_r;
        if (excl <= r && r < incl) { sh_bucket = tid; sh_r = r - excl; }
        __syncthreads();
        prefix |= ((unsigned)sh_bucket) << shift;
        __syncthreads();
    }
    unsigned uthr = (prefix & 0x80000000u) ? (prefix ^ 0x80000000u) : ~prefix;
    float thr = __uint_as_float(uthr);
    int chunk = n / 256;
    int base = tid * chunk;
    int cgt = 0, ceq = 0;
    for (int u = 0; u < chunk; ++u) {
        float s = sc[base + u];
        cgt += (s > thr); ceq += (s == thr);
    }
    sg[tid] = cgt; se[tid] = ceq; __syncthreads();
    for (int off = 1; off < 256; off <<= 1) {
        int vg = (tid >= off) ? sg[tid - off] : 0;
        int ve = (tid >= off) ? se[tid - off] : 0;
        __syncthreads();
        sg[tid] += vg; se[tid] += ve;
        __syncthreads();
    }
    int total_gt = sg[255];
    int ties = k - total_gt;
    int gtb = sg[tid] - cgt, eqb = se[tid] - ceq;
    for (int u = 0; u < chunk; ++u) {
        int i = base + u;
        float s = sc[i];
        bool isgt = (s > thr), iseq = (s == thr);
        bool keep = isgt || (iseq && eqb < ties);
        if (keep) {
            int pos = gtb + (eqb < ties ? eqb : ties);
            idx_local[b * NTOT + pos] = i;
            gate[b * NTOT + pos] = tanhf(s);
            orig_next[b * NTOT + pos] = orig_cur[b * NTOT + i];
        }
        gtb += isgt; eqb += iseq;
    }
}

// gather gated rows, recompute stats, write z, and set inverse map
__global__ void __launch_bounds__(64) gather_kernel(
    const float* __restrict__ h, const int* __restrict__ idx_local,
    const float* __restrict__ gate, const int* __restrict__ orig_new,
    float* __restrict__ hout, float* __restrict__ zout, int* __restrict__ inv,
    int n_old, int k, int tag) {
    int r = blockIdx.x;  // B*k
    int b = r / k, rr = r - b * k;
    int lane = threadIdx.x;
    int src = idx_local[b * NTOT + rr];
    float gg = gate[b * NTOT + rr];
    f32x4 v = ((const f32x4*)h)[(size_t)(b * n_old + src) * 64 + lane] * gg;
    ((f32x4*)hout)[(size_t)r * 64 + lane] = v;
    float s = v[0] + v[1] + v[2] + v[3];
    float ss = v[0] * v[0] + v[1] * v[1] + v[2] * v[2] + v[3] * v[3];
#pragma unroll
    for (int m = 1; m < 64; m <<= 1) { s += __shfl_xor(s, m); ss += __shfl_xor(ss, m); }
    float mean = s * (1.0f / DD);
    float rs = rsqrtf(ss * (1.0f / DD) - mean * mean + 1e-5f);
    f32x4 zv = (v - mean) * rs;
    ((f32x4*)zout)[(size_t)r * 64 + lane] = zv;
    if (lane == 0) inv[b * NTOT + orig_new[b * NTOT + rr]] = (tag << 12) | rr;
}

// ---------------- readout ----------------
__global__ void readout_kernel(const float* __restrict__ h, float* __restrict__ feat) {
    int bd = blockIdx.x;  // B*256
    int b = bd >> 8, d = bd & 255;
    int i = threadIdx.x;
    float x = h[(size_t)(b * 256 + i) * DD + d];
    float m = blockReduceSum256(x) / 256.0f;
    float diff = x - m;
    float s2 = blockReduceSum256(diff * diff);
    if (i == 0) {
        feat[b * 512 + d] = m;
        feat[b * 512 + 256 + d] = sqrtf(s2 / 255.0f) + 1e-6f;
    }
}

__global__ void final_kernel(const float* __restrict__ feat, const float* __restrict__ lw,
                             const float* __restrict__ lb, float* __restrict__ out) {
    int b = blockIdx.x, l = threadIdx.x;  // 128 threads
    float acc = lb[l];
    const float* f = feat + b * 512;
    for (int k = 0; k < 512; ++k) acc += f[k] * lw[k * 128 + l];
    out[b * 128 + l] = acc;
}

extern "C" void kernel_launch(void* const* d_in, const int* in_sizes, int n_in,
                              void* d_out, int out_size, void* d_ws, size_t ws_size,
                              hipStream_t stream) {
    (void)in_sizes; (void)n_in; (void)out_size; (void)ws_size;
    const float* x     = (const float*)d_in[0];
    const float* adj   = (const float*)d_in[1];
    const float* pos   = (const float*)d_in[2];
    const float* in_w  = (const float*)d_in[3];
    const float* in_b  = (const float*)d_in[4];
    const float* pw1   = (const float*)d_in[5];
    const float* pb1   = (const float*)d_in[6];
    const float* pw2   = (const float*)d_in[7];
    const float* pb2   = (const float*)d_in[8];
    const float* bg    = (const float*)d_in[9];
    const float* bb    = (const float*)d_in[10];
    const float* bw1   = (const float*)d_in[11];
    const float* bb1   = (const float*)d_in[12];
    const float* bw2   = (const float*)d_in[13];
    const float* bb2   = (const float*)d_in[14];
    const float* beps  = (const float*)d_in[15];
    const float* poolp = (const float*)d_in[16];
    const float* lw    = (const float*)d_in[17];
    const float* lb    = (const float*)d_in[18];
    float* out = (float*)d_out;

    char* wp = (char*)d_ws;
    auto alloc = [&](size_t bytes) -> void* {
        void* p = (void*)wp;
        wp += (bytes + 255) & ~(size_t)255;
        return p;
    };
    const size_t HBYTES = (size_t)BSZ * NTOT * DD * sizeof(float);  // 8.39 MB
    float*  h    = (float*)alloc(HBYTES);
    float*  bufC = (float*)alloc(HBYTES);          // pe out / gather target
    float*  zA   = (float*)alloc(HBYTES);
    float*  zB   = (float*)alloc(HBYTES);
    half_t* tb   = (half_t*)alloc(HBYTES / 2);     // agg out (f16)
    half_t* Wt   = (half_t*)alloc((size_t)17 * DD * DD * sizeof(half_t));
    float* pstats  = (float*)alloc(8 * sizeof(float));
    float* pinv    = (float*)alloc(4 * sizeof(float));
    float* scores  = (float*)alloc(BSZ * NTOT * sizeof(float));
    float* gate    = (float*)alloc(BSZ * NTOT * sizeof(float));
    int*   origA   = (int*)alloc(BSZ * NTOT * sizeof(int));
    int*   origB   = (int*)alloc(BSZ * NTOT * sizeof(int));
    int*   idxl    = (int*)alloc(BSZ * NTOT * sizeof(int));
    int*   inv     = (int*)alloc(BSZ * NTOT * sizeof(int));
    int*   counts  = (int*)alloc(NTOT * sizeof(int));
    int*   row_ptr = (int*)alloc((NTOT + 1) * sizeof(int));
    int*   col     = (int*)alloc((size_t)NTOT * 64 * sizeof(int));
    int*   ldeg    = (int*)alloc(BSZ * NTOT * sizeof(int));
    int*   lcol    = (int*)alloc((size_t)BSZ * NTOT * 64 * sizeof(int));
    float* feat    = (float*)alloc(BSZ * 512 * sizeof(float));

    // ---- init ----
    wprep_kernel<<<dim3(17, 16, 16), 256, 0, stream>>>(bw1, bw2, pw2, Wt);
    pnorm_kernel<<<3, 256, 0, stream>>>(poolp, pinv);
    pos_stats_kernel<<<1, 256, 0, stream>>>(pos, pstats);
    pe_q_kernel<<<NTOT, 256, 0, stream>>>(pos, pstats, pw1, pb1, tb);
    mm_pe_kernel<<<NTOT / 32, 256, 0, stream>>>(tb, Wt + (size_t)16 * DD * DD, pb2, bufC);
    init_h_kernel<<<BSZ * NTOT, 256, 0, stream>>>(x, in_w, in_b, bufC, h, zA);
    csr_count_kernel<<<NTOT, 256, 0, stream>>>(adj, counts);
    scan_kernel<<<1, 256, 0, stream>>>(counts, row_ptr);
    csr_fill_kernel<<<NTOT, 64, 0, stream>>>(adj, row_ptr, col);
    init_maps_kernel<<<(BSZ * NTOT) / 256, 256, 0, stream>>>(origA, inv);
    build_lcol0_kernel<<<(BSZ * NTOT) / 256, 256, 0, stream>>>(row_ptr, col, ldeg, lcol);

    float* hcur = h;
    float* halt = bufC;
    float* zin = zA;
    float* zout = zB;
    int* orig = origA;
    int* orign = origB;
    int n = NTOT;
    int blk = 0;
    for (int dep = 0; dep < 4; ++dep) {
        for (int s = 0; s < 2; ++s) {
            int rows = BSZ * n;
            agg_kernel<<<rows / 4, 256, 0, stream>>>(zin, tb, bg + blk * DD, bb + blk * DD,
                                                     beps, blk, ldeg, lcol, n);
            if (s == 1 && dep < 3) {
                mlp_kernel<1><<<rows / 32, 256, 0, stream>>>(
                    hcur, tb, zout, Wt + (size_t)blk * DD * DD, Wt + (size_t)(8 + blk) * DD * DD,
                    bb1 + blk * DD, bb2 + blk * DD, poolp, pinv, scores, dep, n);
            } else {
                mlp_kernel<0><<<rows / 32, 256, 0, stream>>>(
                    hcur, tb, zout, Wt + (size_t)blk * DD * DD, Wt + (size_t)(8 + blk) * DD * DD,
                    bb1 + blk * DD, bb2 + blk * DD, nullptr, nullptr, nullptr, 0, n);
            }
            { float* t = zin; zin = zout; zout = t; }
            ++blk;
        }
        if (dep < 3) {
            int k = n / 2;
            topk_kernel<<<BSZ, 256, 0, stream>>>(scores, orig, orign, idxl, gate, n, k);
            { int* t = orig; orig = orign; orign = t; }
            gather_kernel<<<BSZ * k, 64, 0, stream>>>(hcur, idxl, gate, orig, halt, zin, inv,
                                                      n, k, dep + 1);
            { float* t = hcur; hcur = halt; halt = t; }
            build_lcol_kernel<<<(BSZ * k) / 256, 256, 0, stream>>>(row_ptr, col, orig, inv,
                                                                   ldeg, lcol, k, dep + 1);
            n = k;
        }
    }
    // ---- readout ----
    readout_kernel<<<BSZ * 256, 256, 0, stream>>>(hcur, feat);
    final_kernel<<<BSZ, 128, 0, stream>>>(feat, lw, lb, out);
}

// Round 6
// 315.765 us; speedup vs baseline: 1.2258x; 1.1478x over previous
//
#include <hip/hip_runtime.h>
#include <hip/hip_bf16.h>

#define NTOT 2048
#define DD 256
#define BSZ 4

typedef _Float16 half_t;
typedef __attribute__((ext_vector_type(8))) _Float16 halfx8;
typedef __attribute__((ext_vector_type(4))) _Float16 halfx4;
typedef __attribute__((ext_vector_type(4))) float f32x4;

// ---------------- block reduce (256 threads) ----------------
__device__ __forceinline__ float blockReduceSum256(float v) {
    __shared__ float red[4];
    for (int off = 32; off > 0; off >>= 1) v += __shfl_down(v, off);
    int lane = threadIdx.x & 63, w = threadIdx.x >> 6;
    __syncthreads();
    if (lane == 0) red[w] = v;
    __syncthreads();
    return red[0] + red[1] + red[2] + red[3];
}

// ---------------- pos stats ----------------
__global__ void pos_stats_kernel(const float* __restrict__ pos, float* __restrict__ stats) {
    int tid = threadIdx.x;
    float s[3] = {0.f, 0.f, 0.f};
    for (int i = tid; i < NTOT; i += 256)
        for (int c = 0; c < 3; ++c) s[c] += pos[i * 3 + c];
    float m[3];
    for (int c = 0; c < 3; ++c) m[c] = blockReduceSum256(s[c]) / (float)NTOT;
    float q[3] = {0.f, 0.f, 0.f};
    for (int i = tid; i < NTOT; i += 256)
        for (int c = 0; c < 3; ++c) { float d = pos[i * 3 + c] - m[c]; q[c] += d * d; }
    for (int c = 0; c < 3; ++c) {
        float t = blockReduceSum256(q[c]);
        if (tid == 0) {
            float var = ((float)BSZ * t) / ((float)BSZ * NTOT - 1.0f);
            stats[c] = m[c];
            stats[3 + c] = 1.0f / (sqrtf(var) + 1e-8f);
        }
    }
}

__global__ void pnorm_kernel(const float* __restrict__ poolp, float* __restrict__ pinv) {
    int dep = blockIdx.x, tid = threadIdx.x;
    float v = poolp[dep * DD + tid];
    float ss = blockReduceSum256(v * v);
    if (tid == 0) pinv[dep] = rsqrtf(ss);
}

// q[i,d] = silu(pn@pw1 + pb1) -> f16
__global__ void pe_q_kernel(const float* __restrict__ pos, const float* __restrict__ stats,
                            const float* __restrict__ pw1, const float* __restrict__ pb1,
                            half_t* __restrict__ q) {
    int i = blockIdx.x, d = threadIdx.x;
    float acc = pb1[d];
    for (int c = 0; c < 3; ++c) {
        float pn = (pos[i * 3 + c] - stats[c]) * stats[3 + c];
        acc += pn * pw1[c * DD + d];
    }
    acc = acc / (1.0f + expf(-acc));
    q[i * DD + d] = (half_t)acc;
}

// h = x@in_w + in_b + pe; also write z = (h-m)*rstd
__global__ void init_h_kernel(const float* __restrict__ x, const float* __restrict__ in_w,
                              const float* __restrict__ in_b, const float* __restrict__ pe,
                              float* __restrict__ h, float* __restrict__ z) {
    int row = blockIdx.x, d = threadIdx.x;
    float acc = in_b[d];
    for (int k = 0; k < 16; ++k) acc += x[row * 16 + k] * in_w[k * DD + d];
    float v = acc + pe[(row & (NTOT - 1)) * DD + d];
    h[(size_t)row * DD + d] = v;
    float s = blockReduceSum256(v);
    float ss = blockReduceSum256(v * v);
    float mean = s * (1.0f / DD);
    float rs = rsqrtf(ss * (1.0f / DD) - mean * mean + 1e-5f);
    z[(size_t)row * DD + d] = (v - mean) * rs;
}

// ---------------- weight prep: Wt[m][n][k] = f16(W_m[k][n]) ----------------
__global__ void wprep_kernel(const float* __restrict__ bw1, const float* __restrict__ bw2,
                             const float* __restrict__ pw2, half_t* __restrict__ Wt) {
    int m = blockIdx.x, nb = blockIdx.y * 16, kb = blockIdx.z * 16;
    const float* W = (m < 8) ? (bw1 + (size_t)m * DD * DD)
                  : (m < 16) ? (bw2 + (size_t)(m - 8) * DD * DD)
                             : pw2;
    __shared__ float s[16][17];
    int i = threadIdx.x >> 4, j = threadIdx.x & 15;
    s[i][j] = W[(size_t)(kb + i) * DD + nb + j];
    __syncthreads();
    Wt[(size_t)m * DD * DD + (size_t)(nb + i) * DD + kb + j] = (half_t)s[j][i];
}

// ---------------- CSR build (deterministic) ----------------
__global__ void csr_count_kernel(const float* __restrict__ adj, int* __restrict__ counts) {
    int i = blockIdx.x, tid = threadIdx.x;
    float c = 0.f;
    for (int j = tid; j < NTOT; j += 256) c += (adj[(size_t)i * NTOT + j] != 0.f) ? 1.f : 0.f;
    float t = blockReduceSum256(c);
    if (tid == 0) counts[i] = (int)(t + 0.5f);
}

__global__ void scan_kernel(const int* __restrict__ counts, int* __restrict__ row_ptr) {
    __shared__ int csum[256];
    int tid = threadIdx.x;
    int local[8]; int tot = 0;
    for (int u = 0; u < 8; ++u) { local[u] = counts[tid * 8 + u]; tot += local[u]; }
    csum[tid] = tot; __syncthreads();
    for (int off = 1; off < 256; off <<= 1) {
        int v = (tid >= off) ? csum[tid - off] : 0;
        __syncthreads();
        csum[tid] += v;
        __syncthreads();
    }
    int run = csum[tid] - tot;
    for (int u = 0; u < 8; ++u) { row_ptr[tid * 8 + u] = run; run += local[u]; }
    if (tid == 255) row_ptr[NTOT] = run;
}

__global__ void csr_fill_kernel(const float* __restrict__ adj, const int* __restrict__ row_ptr,
                                int* __restrict__ col) {
    int i = blockIdx.x, lane = threadIdx.x;  // 64 threads
    int base = row_ptr[i];
    int run = 0;
    for (int j0 = 0; j0 < NTOT; j0 += 64) {
        int j = j0 + lane;
        bool pred = adj[(size_t)i * NTOT + j] != 0.f;
        unsigned long long mask = __ballot(pred);
        if (pred) {
            int pos = run + __popcll(mask & ((1ull << lane) - 1ull));
            col[base + pos] = j;
        }
        run += __popcll(mask);
    }
}

// ---------------- maps / local neighbor lists ----------------
__global__ void init_maps_kernel(int* __restrict__ orig, int* __restrict__ inv) {
    int t = blockIdx.x * 256 + threadIdx.x;  // B*N
    int i = t & (NTOT - 1);
    orig[t] = i; inv[t] = i;  // tag 0
}

__global__ void build_lcol_kernel(const int* __restrict__ row_ptr, const int* __restrict__ col,
                                  const int* __restrict__ orig, const int* __restrict__ inv,
                                  int* __restrict__ ldeg, int* __restrict__ lcol, int k, int tag) {
    int t = blockIdx.x * 256 + threadIdx.x;  // B*k
    int b = t / k, i = t - b * k;
    int key = b * NTOT + i;
    int o = orig[key];
    int s = row_ptr[o], e = row_ptr[o + 1];
    const int* invb = inv + b * NTOT;
    int cnt = 0;
    for (int p = s; p < e && cnt < 64; ++p) {
        int v = invb[col[p]];
        if ((v >> 12) == tag) { lcol[(size_t)key * 64 + cnt] = v & 4095; ++cnt; }
    }
    ldeg[key] = cnt;
}

// ---------------- standalone aggregation: one wave per row ----------------
// t = g*(eps1*z_s + sum_j z_j) + (eps1+deg)*b  -> f16 tb
// lvl0: read CSR directly (local==global idx); else padded lcol/ldeg.
__global__ void __launch_bounds__(256) agg_kernel(
    const float* __restrict__ zin, half_t* __restrict__ tb,
    const float* __restrict__ gv, const float* __restrict__ bbv,
    const float* __restrict__ beps, int blk,
    const int* __restrict__ row_ptr, const int* __restrict__ col,
    const int* __restrict__ ldeg, const int* __restrict__ lcol, int n, int lvl0) {
    int w = threadIdx.x >> 6, lane = threadIdx.x & 63;
    int r = blockIdx.x * 4 + w;  // 0..B*n-1
    int b = r / n, i = r - b * n;
    float eps1 = 1.0f + beps[blk];
    const f32x4* zb = (const f32x4*)zin + (size_t)b * n * 64;
    f32x4 acc = zb[(size_t)i * 64 + lane] * eps1;
    int deg;
    const int* lc;
    if (lvl0) {
        int s = row_ptr[i];
        deg = row_ptr[i + 1] - s;
        lc = col + s;
    } else {
        int key = b * NTOT + i;
        deg = ldeg[key];
        lc = lcol + (size_t)key * 64;
    }
    int p = 0;
    for (; p + 4 <= deg; p += 4) {
        int j0 = lc[p], j1 = lc[p + 1], j2 = lc[p + 2], j3 = lc[p + 3];
        f32x4 v0 = zb[(size_t)j0 * 64 + lane];
        f32x4 v1 = zb[(size_t)j1 * 64 + lane];
        f32x4 v2 = zb[(size_t)j2 * 64 + lane];
        f32x4 v3 = zb[(size_t)j3 * 64 + lane];
        acc += (v0 + v1) + (v2 + v3);
    }
    for (; p < deg; ++p) acc += zb[(size_t)lc[p] * 64 + lane];
    float coefb = eps1 + (float)deg;
    f32x4 gvv = ((const f32x4*)gv)[lane];
    f32x4 bvv = ((const f32x4*)bbv)[lane];
    f32x4 tv = gvv * acc + bvv * coefb;
    halfx4 th;
#pragma unroll
    for (int e = 0; e < 4; ++e) th[e] = (half_t)tv[e];
    ((halfx4*)tb)[(size_t)r * 64 + lane] = th;
}

// ---------------- fused MLP: 16 rows/block, 256 thr (4 waves x 64 cols) ----------------
// mm1+silu -> LDS ub -> mm2 + residual/stats/z (+score). A read from global tb.
template <int SCORE>
__global__ void __launch_bounds__(256) mlp_kernel(
    float* __restrict__ h, const half_t* __restrict__ tb, float* __restrict__ zout,
    const half_t* __restrict__ Wt1, const half_t* __restrict__ Wt2,
    const float* __restrict__ b1v, const float* __restrict__ b2v,
    const float* __restrict__ poolp, const float* __restrict__ pinv_all,
    float* __restrict__ scores, int dep, int n) {
    __shared__ half_t ub[16][264];
    __shared__ float part[4][16][3];
    __shared__ float mrs[16][2];
    int tid = threadIdx.x;
    int rowBase = blockIdx.x * 16;
    int w = tid >> 6, l = tid & 63;
    int lo = l & 15, hi = l >> 4;
    int kb = hi * 8;

    // ---- mm1 + silu -> ub ----
    {
        const half_t* a0p = tb + (size_t)(rowBase + lo) * DD + kb;
        f32x4 acc[4] = {};
#pragma unroll
        for (int k0 = 0; k0 < DD; k0 += 32) {
            halfx8 a0 = *(const halfx8*)(a0p + k0);
#pragma unroll
            for (int j = 0; j < 4; ++j) {
                halfx8 bj = *(const halfx8*)(Wt1 + (size_t)(w * 64 + j * 16 + lo) * DD + kb + k0);
                acc[j] = __builtin_amdgcn_mfma_f32_16x16x32_f16(a0, bj, acc[j], 0, 0, 0);
            }
        }
        float bs[4];
#pragma unroll
        for (int j = 0; j < 4; ++j) bs[j] = b1v[w * 64 + j * 16 + lo];
#pragma unroll
        for (int q = 0; q < 4; ++q)
#pragma unroll
            for (int j = 0; j < 4; ++j) {
                float v = acc[j][q] + bs[j];
                v = v / (1.0f + expf(-v));
                ub[hi * 4 + q][w * 64 + j * 16 + lo] = (half_t)v;
            }
    }
    __syncthreads();

    // ---- mm2 + residual + stats (+score) + z ----
    {
        f32x4 acc[4] = {};
#pragma unroll
        for (int k0 = 0; k0 < DD; k0 += 32) {
            halfx8 a0 = *(const halfx8*)&ub[lo][kb + k0];
#pragma unroll
            for (int j = 0; j < 4; ++j) {
                halfx8 bj = *(const halfx8*)(Wt2 + (size_t)(w * 64 + j * 16 + lo) * DD + kb + k0);
                acc[j] = __builtin_amdgcn_mfma_f32_16x16x32_f16(a0, bj, acc[j], 0, 0, 0);
            }
        }
        float bs[4], pv[4] = {};
#pragma unroll
        for (int j = 0; j < 4; ++j) bs[j] = b2v[w * 64 + j * 16 + lo];
        if (SCORE) {
#pragma unroll
            for (int j = 0; j < 4; ++j) pv[j] = poolp[dep * DD + w * 64 + j * 16 + lo];
        }
        float vh[4][4];
#pragma unroll
        for (int q = 0; q < 4; ++q) {
            int r = rowBase + hi * 4 + q;
            float s = 0.f, ss = 0.f, sp = 0.f;
#pragma unroll
            for (int j = 0; j < 4; ++j) {
                int c = w * 64 + j * 16 + lo;
                float v = h[(size_t)r * DD + c] + acc[j][q] + bs[j];
                vh[j][q] = v;
                s += v; ss += v * v;
                if (SCORE) sp += v * pv[j];
            }
#pragma unroll
            for (int m = 1; m < 16; m <<= 1) {
                s += __shfl_xor(s, m); ss += __shfl_xor(ss, m);
                if (SCORE) sp += __shfl_xor(sp, m);
            }
            if (lo == 0) {
                int rl = hi * 4 + q;
                part[w][rl][0] = s; part[w][rl][1] = ss;
                if (SCORE) part[w][rl][2] = sp;
            }
        }
        __syncthreads();
        if (tid < 16) {
            float s = 0.f, ss = 0.f, sp = 0.f;
#pragma unroll
            for (int w2 = 0; w2 < 4; ++w2) {
                s += part[w2][tid][0]; ss += part[w2][tid][1];
                if (SCORE) sp += part[w2][tid][2];
            }
            float mean = s * (1.0f / DD);
            float var = ss * (1.0f / DD) - mean * mean;
            mrs[tid][0] = mean;
            mrs[tid][1] = rsqrtf(var + 1e-5f);
            if (SCORE) {
                int r = rowBase + tid;
                int b2 = r / n, ii = r - b2 * n;
                scores[b2 * NTOT + ii] = sp * pinv_all[dep];
            }
        }
        __syncthreads();
#pragma unroll
        for (int q = 0; q < 4; ++q) {
            int rl = hi * 4 + q;
            int r = rowBase + rl;
            float mean = mrs[rl][0], rs = mrs[rl][1];
#pragma unroll
            for (int j = 0; j < 4; ++j) {
                int c = w * 64 + j * 16 + lo;
                float v = vh[j][q];
                h[(size_t)r * DD + c] = v;
                zout[(size_t)r * DD + c] = (v - mean) * rs;
            }
        }
    }
}

// ---------------- standalone mm for positional embedding (16 rows/block) ----------------
__global__ void __launch_bounds__(256) mm_pe_kernel(const half_t* __restrict__ A,
                                                    const half_t* __restrict__ Wt,
                                                    const float* __restrict__ bias,
                                                    float* __restrict__ C) {
    int tid = threadIdx.x;
    int w = tid >> 6, l = tid & 63;
    int lo = l & 15, hi = l >> 4;
    int rowBase = blockIdx.x * 16;
    int kb = hi * 8;
    const half_t* a0p = A + (size_t)(rowBase + lo) * DD + kb;
    f32x4 acc[4] = {};
#pragma unroll
    for (int k0 = 0; k0 < DD; k0 += 32) {
        halfx8 a0 = *(const halfx8*)(a0p + k0);
#pragma unroll
        for (int j = 0; j < 4; ++j) {
            halfx8 bj = *(const halfx8*)(Wt + (size_t)(w * 64 + j * 16 + lo) * DD + kb + k0);
            acc[j] = __builtin_amdgcn_mfma_f32_16x16x32_f16(a0, bj, acc[j], 0, 0, 0);
        }
    }
#pragma unroll
    for (int q = 0; q < 4; ++q)
#pragma unroll
        for (int j = 0; j < 4; ++j) {
            int r = rowBase + hi * 4 + q;
            int c = w * 64 + j * 16 + lo;
            C[(size_t)r * DD + c] = acc[j][q] + bias[c];
        }
}

// ---------------- pooling ----------------
__global__ void topk_kernel(const float* __restrict__ scores, const int* __restrict__ orig_cur,
                            int* __restrict__ orig_next, int* __restrict__ idx_local,
                            float* __restrict__ gate, int n, int k) {
    __shared__ unsigned keys[2048];
    __shared__ int hist[256];
    __shared__ int sg[256], se[256];
    __shared__ int sh_bucket, sh_r;
    int b = blockIdx.x;
    const float* sc = scores + b * NTOT;
    int tid = threadIdx.x;
    for (int i = tid; i < n; i += 256) {
        unsigned u = __float_as_uint(sc[i]);
        keys[i] = (u & 0x80000000u) ? ~u : (u | 0x80000000u);
    }
    if (tid == 0) sh_r = n - k;
    __syncthreads();
    unsigned prefix = 0;
    for (int shift = 24; shift >= 0; shift -= 8) {
        hist[tid] = 0;
        __syncthreads();
        unsigned mask = (shift == 24) ? 0u : (0xFFFFFFFFu << (shift + 8));
        for (int i = tid; i < n; i += 256) {
            unsigned key = keys[i];
            if ((key & mask) == (prefix & mask))
                atomicAdd(&hist[(key >> shift) & 255], 1);
        }
        __syncthreads();
        int cnt = hist[tid];
        sg[tid] = cnt;
        __syncthreads();
        for (int off = 1; off < 256; off <<= 1) {
            int v = (tid >= off) ? sg[tid - off] : 0;
            __syncthreads();
            sg[tid] += v;
            __syncthreads();
        }
        int incl = sg[tid], excl = incl - cnt;
        int r = sh_r;
        if (excl <= r && r < incl) { sh_bucket = tid; sh_r = r - excl; }
        __syncthreads();
        prefix |= ((unsigned)sh_bucket) << shift;
        __syncthreads();
    }
    unsigned uthr = (prefix & 0x80000000u) ? (prefix ^ 0x80000000u) : ~prefix;
    float thr = __uint_as_float(uthr);
    int chunk = n / 256;
    int base = tid * chunk;
    int cgt = 0, ceq = 0;
    for (int u = 0; u < chunk; ++u) {
        float s = sc[base + u];
        cgt += (s > thr); ceq += (s == thr);
    }
    sg[tid] = cgt; se[tid] = ceq; __syncthreads();
    for (int off = 1; off < 256; off <<= 1) {
        int vg = (tid >= off) ? sg[tid - off] : 0;
        int ve = (tid >= off) ? se[tid - off] : 0;
        __syncthreads();
        sg[tid] += vg; se[tid] += ve;
        __syncthreads();
    }
    int total_gt = sg[255];
    int ties = k - total_gt;
    int gtb = sg[tid] - cgt, eqb = se[tid] - ceq;
    for (int u = 0; u < chunk; ++u) {
        int i = base + u;
        float s = sc[i];
        bool isgt = (s > thr), iseq = (s == thr);
        bool keep = isgt || (iseq && eqb < ties);
        if (keep) {
            int pos = gtb + (eqb < ties ? eqb : ties);
            idx_local[b * NTOT + pos] = i;
            gate[b * NTOT + pos] = tanhf(s);
            orig_next[b * NTOT + pos] = orig_cur[b * NTOT + i];
        }
        gtb += isgt; eqb += iseq;
    }
}

// gather gated rows, recompute stats, write z, and set inverse map
__global__ void __launch_bounds__(64) gather_kernel(
    const float* __restrict__ h, const int* __restrict__ idx_local,
    const float* __restrict__ gate, const int* __restrict__ orig_new,
    float* __restrict__ hout, float* __restrict__ zout, int* __restrict__ inv,
    int n_old, int k, int tag) {
    int r = blockIdx.x;  // B*k
    int b = r / k, rr = r - b * k;
    int lane = threadIdx.x;
    int src = idx_local[b * NTOT + rr];
    float gg = gate[b * NTOT + rr];
    f32x4 v = ((const f32x4*)h)[(size_t)(b * n_old + src) * 64 + lane] * gg;
    ((f32x4*)hout)[(size_t)r * 64 + lane] = v;
    float s = v[0] + v[1] + v[2] + v[3];
    float ss = v[0] * v[0] + v[1] * v[1] + v[2] * v[2] + v[3] * v[3];
#pragma unroll
    for (int m = 1; m < 64; m <<= 1) { s += __shfl_xor(s, m); ss += __shfl_xor(ss, m); }
    float mean = s * (1.0f / DD);
    float rs = rsqrtf(ss * (1.0f / DD) - mean * mean + 1e-5f);
    f32x4 zv = (v - mean) * rs;
    ((f32x4*)zout)[(size_t)r * 64 + lane] = zv;
    if (lane == 0) inv[b * NTOT + orig_new[b * NTOT + rr]] = (tag << 12) | rr;
}

// ---------------- readout ----------------
__global__ void readout_kernel(const float* __restrict__ h, float* __restrict__ feat) {
    int bd = blockIdx.x;  // B*256
    int b = bd >> 8, d = bd & 255;
    int i = threadIdx.x;
    float x = h[(size_t)(b * 256 + i) * DD + d];
    float m = blockReduceSum256(x) / 256.0f;
    float diff = x - m;
    float s2 = blockReduceSum256(diff * diff);
    if (i == 0) {
        feat[b * 512 + d] = m;
        feat[b * 512 + 256 + d] = sqrtf(s2 / 255.0f) + 1e-6f;
    }
}

__global__ void final_kernel(const float* __restrict__ feat, const float* __restrict__ lw,
                             const float* __restrict__ lb, float* __restrict__ out) {
    int b = blockIdx.x, l = threadIdx.x;  // 128 threads
    float acc = lb[l];
    const float* f = feat + b * 512;
    for (int k = 0; k < 512; ++k) acc += f[k] * lw[k * 128 + l];
    out[b * 128 + l] = acc;
}

extern "C" void kernel_launch(void* const* d_in, const int* in_sizes, int n_in,
                              void* d_out, int out_size, void* d_ws, size_t ws_size,
                              hipStream_t stream) {
    (void)in_sizes; (void)n_in; (void)out_size; (void)ws_size;
    const float* x     = (const float*)d_in[0];
    const float* adj   = (const float*)d_in[1];
    const float* pos   = (const float*)d_in[2];
    const float* in_w  = (const float*)d_in[3];
    const float* in_b  = (const float*)d_in[4];
    const float* pw1   = (const float*)d_in[5];
    const float* pb1   = (const float*)d_in[6];
    const float* pw2   = (const float*)d_in[7];
    const float* pb2   = (const float*)d_in[8];
    const float* bg    = (const float*)d_in[9];
    const float* bb    = (const float*)d_in[10];
    const float* bw1   = (const float*)d_in[11];
    const float* bb1   = (const float*)d_in[12];
    const float* bw2   = (const float*)d_in[13];
    const float* bb2   = (const float*)d_in[14];
    const float* beps  = (const float*)d_in[15];
    const float* poolp = (const float*)d_in[16];
    const float* lw    = (const float*)d_in[17];
    const float* lb    = (const float*)d_in[18];
    float* out = (float*)d_out;

    char* wp = (char*)d_ws;
    auto alloc = [&](size_t bytes) -> void* {
        void* p = (void*)wp;
        wp += (bytes + 255) & ~(size_t)255;
        return p;
    };
    const size_t HBYTES = (size_t)BSZ * NTOT * DD * sizeof(float);  // 8.39 MB
    float*  h    = (float*)alloc(HBYTES);
    float*  bufC = (float*)alloc(HBYTES);          // pe out / gather target
    float*  zA   = (float*)alloc(HBYTES);
    float*  zB   = (float*)alloc(HBYTES);
    half_t* tb   = (half_t*)alloc(HBYTES / 2);     // agg out (f16)
    half_t* Wt   = (half_t*)alloc((size_t)17 * DD * DD * sizeof(half_t));
    float* pstats  = (float*)alloc(8 * sizeof(float));
    float* pinv    = (float*)alloc(4 * sizeof(float));
    float* scores  = (float*)alloc(BSZ * NTOT * sizeof(float));
    float* gate    = (float*)alloc(BSZ * NTOT * sizeof(float));
    int*   origA   = (int*)alloc(BSZ * NTOT * sizeof(int));
    int*   origB   = (int*)alloc(BSZ * NTOT * sizeof(int));
    int*   idxl    = (int*)alloc(BSZ * NTOT * sizeof(int));
    int*   inv     = (int*)alloc(BSZ * NTOT * sizeof(int));
    int*   counts  = (int*)alloc(NTOT * sizeof(int));
    int*   row_ptr = (int*)alloc((NTOT + 1) * sizeof(int));
    int*   col     = (int*)alloc((size_t)NTOT * 64 * sizeof(int));
    int*   ldeg    = (int*)alloc(BSZ * NTOT * sizeof(int));
    int*   lcol    = (int*)alloc((size_t)BSZ * NTOT * 64 * sizeof(int));
    float* feat    = (float*)alloc(BSZ * 512 * sizeof(float));

    // ---- init ----
    wprep_kernel<<<dim3(17, 16, 16), 256, 0, stream>>>(bw1, bw2, pw2, Wt);
    pnorm_kernel<<<3, 256, 0, stream>>>(poolp, pinv);
    pos_stats_kernel<<<1, 256, 0, stream>>>(pos, pstats);
    pe_q_kernel<<<NTOT, 256, 0, stream>>>(pos, pstats, pw1, pb1, tb);
    mm_pe_kernel<<<NTOT / 16, 256, 0, stream>>>(tb, Wt + (size_t)16 * DD * DD, pb2, bufC);
    init_h_kernel<<<BSZ * NTOT, 256, 0, stream>>>(x, in_w, in_b, bufC, h, zA);
    csr_count_kernel<<<NTOT, 256, 0, stream>>>(adj, counts);
    scan_kernel<<<1, 256, 0, stream>>>(counts, row_ptr);
    csr_fill_kernel<<<NTOT, 64, 0, stream>>>(adj, row_ptr, col);
    init_maps_kernel<<<(BSZ * NTOT) / 256, 256, 0, stream>>>(origA, inv);

    float* hcur = h;
    float* halt = bufC;
    float* zin = zA;
    float* zout = zB;
    int* orig = origA;
    int* orign = origB;
    int n = NTOT;
    int blk = 0;
    for (int dep = 0; dep < 4; ++dep) {
        for (int s = 0; s < 2; ++s) {
            int rows = BSZ * n;
            agg_kernel<<<rows / 4, 256, 0, stream>>>(zin, tb, bg + blk * DD, bb + blk * DD,
                                                     beps, blk, row_ptr, col, ldeg, lcol, n,
                                                     dep == 0 ? 1 : 0);
            if (s == 1 && dep < 3) {
                mlp_kernel<1><<<rows / 16, 256, 0, stream>>>(
                    hcur, tb, zout, Wt + (size_t)blk * DD * DD, Wt + (size_t)(8 + blk) * DD * DD,
                    bb1 + blk * DD, bb2 + blk * DD, poolp, pinv, scores, dep, n);
            } else {
                mlp_kernel<0><<<rows / 16, 256, 0, stream>>>(
                    hcur, tb, zout, Wt + (size_t)blk * DD * DD, Wt + (size_t)(8 + blk) * DD * DD,
                    bb1 + blk * DD, bb2 + blk * DD, nullptr, nullptr, nullptr, 0, n);
            }
            { float* t = zin; zin = zout; zout = t; }
            ++blk;
        }
        if (dep < 3) {
            int k = n / 2;
            topk_kernel<<<BSZ, 256, 0, stream>>>(scores, orig, orign, idxl, gate, n, k);
            { int* t = orig; orig = orign; orign = t; }
            gather_kernel<<<BSZ * k, 64, 0, stream>>>(hcur, idxl, gate, orig, halt, zin, inv,
                                                      n, k, dep + 1);
            { float* t = hcur; hcur = halt; halt = t; }
            build_lcol_kernel<<<(BSZ * k) / 256, 256, 0, stream>>>(row_ptr, col, orig, inv,
                                                                   ldeg, lcol, k, dep + 1);
            n = k;
        }
    }
    // ---- readout ----
    readout_kernel<<<BSZ * 256, 256, 0, stream>>>(hcur, feat);
    final_kernel<<<BSZ, 128, 0, stream>>>(feat, lw, lb, out);
}

// Round 7
// 294.774 us; speedup vs baseline: 1.3131x; 1.0712x over previous
//
#include <hip/hip_runtime.h>
#include <hip/hip_bf16.h>

#define NTOT 2048
#define DD 256
#define BSZ 4

typedef _Float16 half_t;
typedef __attribute__((ext_vector_type(8))) _Float16 halfx8;
typedef __attribute__((ext_vector_type(4))) _Float16 halfx4;
typedef __attribute__((ext_vector_type(4))) float f32x4;

// ---------------- block reduce (256 threads) ----------------
__device__ __forceinline__ float blockReduceSum256(float v) {
    __shared__ float red[4];
    for (int off = 32; off > 0; off >>= 1) v += __shfl_down(v, off);
    int lane = threadIdx.x & 63, w = threadIdx.x >> 6;
    __syncthreads();
    if (lane == 0) red[w] = v;
    __syncthreads();
    return red[0] + red[1] + red[2] + red[3];
}

// ---------------- merged setup stats: block 0 = pos stats, blocks 1-3 = pool norms ----------------
__global__ void stats_kernel(const float* __restrict__ pos, float* __restrict__ pstats,
                             const float* __restrict__ poolp, float* __restrict__ pinv) {
    int tid = threadIdx.x;
    if (blockIdx.x == 0) {
        float s[3] = {0.f, 0.f, 0.f};
        for (int i = tid; i < NTOT; i += 256)
            for (int c = 0; c < 3; ++c) s[c] += pos[i * 3 + c];
        float m[3];
        for (int c = 0; c < 3; ++c) m[c] = blockReduceSum256(s[c]) / (float)NTOT;
        float q[3] = {0.f, 0.f, 0.f};
        for (int i = tid; i < NTOT; i += 256)
            for (int c = 0; c < 3; ++c) { float d = pos[i * 3 + c] - m[c]; q[c] += d * d; }
        for (int c = 0; c < 3; ++c) {
            float t = blockReduceSum256(q[c]);
            if (tid == 0) {
                float var = ((float)BSZ * t) / ((float)BSZ * NTOT - 1.0f);
                pstats[c] = m[c];
                pstats[3 + c] = 1.0f / (sqrtf(var) + 1e-8f);
            }
        }
    } else {
        int dep = blockIdx.x - 1;
        float v = poolp[dep * DD + tid];
        float ss = blockReduceSum256(v * v);
        if (tid == 0) pinv[dep] = rsqrtf(ss);
    }
}

// q[i,d] = silu(pn@pw1 + pb1) -> f16
__global__ void pe_q_kernel(const float* __restrict__ pos, const float* __restrict__ stats,
                            const float* __restrict__ pw1, const float* __restrict__ pb1,
                            half_t* __restrict__ q) {
    int i = blockIdx.x, d = threadIdx.x;
    float acc = pb1[d];
    for (int c = 0; c < 3; ++c) {
        float pn = (pos[i * 3 + c] - stats[c]) * stats[3 + c];
        acc += pn * pw1[c * DD + d];
    }
    acc = acc / (1.0f + expf(-acc));
    q[i * DD + d] = (half_t)acc;
}

// h = x@in_w + in_b + pe; also write z = (h-m)*rstd
__global__ void init_h_kernel(const float* __restrict__ x, const float* __restrict__ in_w,
                              const float* __restrict__ in_b, const float* __restrict__ pe,
                              float* __restrict__ h, float* __restrict__ z) {
    int row = blockIdx.x, d = threadIdx.x;
    float acc = in_b[d];
    for (int k = 0; k < 16; ++k) acc += x[row * 16 + k] * in_w[k * DD + d];
    float v = acc + pe[(row & (NTOT - 1)) * DD + d];
    h[(size_t)row * DD + d] = v;
    float s = blockReduceSum256(v);
    float ss = blockReduceSum256(v * v);
    float mean = s * (1.0f / DD);
    float rs = rsqrtf(ss * (1.0f / DD) - mean * mean + 1e-5f);
    z[(size_t)row * DD + d] = (v - mean) * rs;
}

// ---------------- weight prep: Wt[m][n][k] = f16(W_m[k][n]) ----------------
__global__ void wprep_kernel(const float* __restrict__ bw1, const float* __restrict__ bw2,
                             const float* __restrict__ pw2, half_t* __restrict__ Wt) {
    int m = blockIdx.x, nb = blockIdx.y * 16, kb = blockIdx.z * 16;
    const float* W = (m < 8) ? (bw1 + (size_t)m * DD * DD)
                  : (m < 16) ? (bw2 + (size_t)(m - 8) * DD * DD)
                             : pw2;
    __shared__ float s[16][17];
    int i = threadIdx.x >> 4, j = threadIdx.x & 15;
    s[i][j] = W[(size_t)(kb + i) * DD + nb + j];
    __syncthreads();
    Wt[(size_t)m * DD * DD + (size_t)(nb + i) * DD + kb + j] = (half_t)s[j][i];
}

// ---------------- CSR build (deterministic) ----------------
__global__ void csr_count_kernel(const float* __restrict__ adj, int* __restrict__ counts) {
    int i = blockIdx.x, tid = threadIdx.x;
    float c = 0.f;
    for (int j = tid; j < NTOT; j += 256) c += (adj[(size_t)i * NTOT + j] != 0.f) ? 1.f : 0.f;
    float t = blockReduceSum256(c);
    if (tid == 0) counts[i] = (int)(t + 0.5f);
}

__global__ void scan_kernel(const int* __restrict__ counts, int* __restrict__ row_ptr) {
    __shared__ int csum[256];
    int tid = threadIdx.x;
    int local[8]; int tot = 0;
    for (int u = 0; u < 8; ++u) { local[u] = counts[tid * 8 + u]; tot += local[u]; }
    csum[tid] = tot; __syncthreads();
    for (int off = 1; off < 256; off <<= 1) {
        int v = (tid >= off) ? csum[tid - off] : 0;
        __syncthreads();
        csum[tid] += v;
        __syncthreads();
    }
    int run = csum[tid] - tot;
    for (int u = 0; u < 8; ++u) { row_ptr[tid * 8 + u] = run; run += local[u]; }
    if (tid == 255) row_ptr[NTOT] = run;
}

__global__ void csr_fill_kernel(const float* __restrict__ adj, const int* __restrict__ row_ptr,
                                int* __restrict__ col) {
    int i = blockIdx.x, lane = threadIdx.x;  // 64 threads
    int base = row_ptr[i];
    int run = 0;
    for (int j0 = 0; j0 < NTOT; j0 += 64) {
        int j = j0 + lane;
        bool pred = adj[(size_t)i * NTOT + j] != 0.f;
        unsigned long long mask = __ballot(pred);
        if (pred) {
            int pos = run + __popcll(mask & ((1ull << lane) - 1ull));
            col[base + pos] = j;
        }
        run += __popcll(mask);
    }
}

// ---------------- maps / local neighbor lists ----------------
__global__ void init_maps_kernel(int* __restrict__ orig, int* __restrict__ inv) {
    int t = blockIdx.x * 256 + threadIdx.x;  // B*N
    int i = t & (NTOT - 1);
    orig[t] = i; inv[t] = i;  // tag 0
}

__global__ void build_lcol_kernel(const int* __restrict__ row_ptr, const int* __restrict__ col,
                                  const int* __restrict__ orig, const int* __restrict__ inv,
                                  int* __restrict__ ldeg, int* __restrict__ lcol, int k, int tag) {
    int t = blockIdx.x * 256 + threadIdx.x;  // B*k
    int b = t / k, i = t - b * k;
    int key = b * NTOT + i;
    int o = orig[key];
    int s = row_ptr[o], e = row_ptr[o + 1];
    const int* invb = inv + b * NTOT;
    int cnt = 0;
    for (int p = s; p < e && cnt < 64; ++p) {
        int v = invb[col[p]];
        if ((v >> 12) == tag) { lcol[(size_t)key * 64 + cnt] = v & 4095; ++cnt; }
    }
    ldeg[key] = cnt;
}

// ---------------- fused layer: agg (LDS) -> mm1+silu (LDS) -> mm2 + residual/stats/z (+score) ----
// 16 rows/block, 256 thr (4 waves x 64 cols). Phase A: 16 thr/row neighbor-sum of zin.
template <int SCORE>
__global__ void __launch_bounds__(256) layer_kernel(
    float* __restrict__ h, const float* __restrict__ zin, float* __restrict__ zout,
    const half_t* __restrict__ Wt1, const half_t* __restrict__ Wt2,
    const float* __restrict__ b1v, const float* __restrict__ b2v,
    const float* __restrict__ gv, const float* __restrict__ bbv,
    const float* __restrict__ beps, int blk,
    const int* __restrict__ row_ptr, const int* __restrict__ col,
    const int* __restrict__ ldeg, const int* __restrict__ lcol,
    const float* __restrict__ poolp, const float* __restrict__ pinv_all,
    float* __restrict__ scores, int dep, int n, int lvl0) {
    __shared__ half_t tb[16][264];
    __shared__ half_t ub[16][264];
    __shared__ float part[4][16][3];
    __shared__ float mrs[16][2];
    int tid = threadIdx.x;
    int rowBase = blockIdx.x * 16;
    float eps1 = 1.0f + beps[blk];

    // ---- phase A: aggregation -> LDS tb (f16) ----
    {
        int rl = tid >> 4, cg = tid & 15;   // 16 thr/row, 4 f32x4 chunks each
        int r = rowBase + rl;
        int b = r / n, i = r - b * n;
        const f32x4* zb = (const f32x4*)zin + (size_t)b * n * 64;
        f32x4 acc[4];
#pragma unroll
        for (int u = 0; u < 4; ++u) acc[u] = zb[(size_t)i * 64 + cg + 16 * u] * eps1;
        int deg; const int* lc;
        if (lvl0) {
            int s = row_ptr[i];
            deg = row_ptr[i + 1] - s;
            lc = col + s;
        } else {
            int key = b * NTOT + i;
            deg = ldeg[key];
            lc = lcol + (size_t)key * 64;
        }
        int p = 0;
        for (; p + 4 <= deg; p += 4) {
            int j0 = lc[p], j1 = lc[p + 1], j2 = lc[p + 2], j3 = lc[p + 3];
#pragma unroll
            for (int u = 0; u < 4; ++u) {
                f32x4 v0 = zb[(size_t)j0 * 64 + cg + 16 * u];
                f32x4 v1 = zb[(size_t)j1 * 64 + cg + 16 * u];
                f32x4 v2 = zb[(size_t)j2 * 64 + cg + 16 * u];
                f32x4 v3 = zb[(size_t)j3 * 64 + cg + 16 * u];
                acc[u] += (v0 + v1) + (v2 + v3);
            }
        }
        for (; p < deg; ++p) {
            int j = lc[p];
#pragma unroll
            for (int u = 0; u < 4; ++u) acc[u] += zb[(size_t)j * 64 + cg + 16 * u];
        }
        float coefb = eps1 + (float)deg;
#pragma unroll
        for (int u = 0; u < 4; ++u) {
            int c4 = cg + 16 * u;
            f32x4 gvv = ((const f32x4*)gv)[c4];
            f32x4 bvv = ((const f32x4*)bbv)[c4];
            f32x4 tv = gvv * acc[u] + bvv * coefb;
            halfx4 th;
#pragma unroll
            for (int e = 0; e < 4; ++e) th[e] = (half_t)tv[e];
            *(halfx4*)&tb[rl][c4 * 4] = th;
        }
    }
    __syncthreads();

    int w = tid >> 6, l = tid & 63;
    int lo = l & 15, hi = l >> 4;
    int kb = hi * 8;

    // ---- phase B: mm1 + silu -> ub ----
    {
        f32x4 acc[4] = {};
#pragma unroll
        for (int k0 = 0; k0 < DD; k0 += 32) {
            halfx8 a0 = *(const halfx8*)&tb[lo][kb + k0];
#pragma unroll
            for (int j = 0; j < 4; ++j) {
                halfx8 bj = *(const halfx8*)(Wt1 + (size_t)(w * 64 + j * 16 + lo) * DD + kb + k0);
                acc[j] = __builtin_amdgcn_mfma_f32_16x16x32_f16(a0, bj, acc[j], 0, 0, 0);
            }
        }
        float bs[4];
#pragma unroll
        for (int j = 0; j < 4; ++j) bs[j] = b1v[w * 64 + j * 16 + lo];
#pragma unroll
        for (int q = 0; q < 4; ++q)
#pragma unroll
            for (int j = 0; j < 4; ++j) {
                float v = acc[j][q] + bs[j];
                v = v / (1.0f + expf(-v));
                ub[hi * 4 + q][w * 64 + j * 16 + lo] = (half_t)v;
            }
    }
    __syncthreads();

    // ---- phase C: mm2 + residual + stats (+score) + z ----
    {
        f32x4 acc[4] = {};
#pragma unroll
        for (int k0 = 0; k0 < DD; k0 += 32) {
            halfx8 a0 = *(const halfx8*)&ub[lo][kb + k0];
#pragma unroll
            for (int j = 0; j < 4; ++j) {
                halfx8 bj = *(const halfx8*)(Wt2 + (size_t)(w * 64 + j * 16 + lo) * DD + kb + k0);
                acc[j] = __builtin_amdgcn_mfma_f32_16x16x32_f16(a0, bj, acc[j], 0, 0, 0);
            }
        }
        float bs[4], pv[4] = {};
#pragma unroll
        for (int j = 0; j < 4; ++j) bs[j] = b2v[w * 64 + j * 16 + lo];
        if (SCORE) {
#pragma unroll
            for (int j = 0; j < 4; ++j) pv[j] = poolp[dep * DD + w * 64 + j * 16 + lo];
        }
        float vh[4][4];
#pragma unroll
        for (int q = 0; q < 4; ++q) {
            int r = rowBase + hi * 4 + q;
            float s = 0.f, ss = 0.f, sp = 0.f;
#pragma unroll
            for (int j = 0; j < 4; ++j) {
                int c = w * 64 + j * 16 + lo;
                float v = h[(size_t)r * DD + c] + acc[j][q] + bs[j];
                vh[j][q] = v;
                s += v; ss += v * v;
                if (SCORE) sp += v * pv[j];
            }
#pragma unroll
            for (int m = 1; m < 16; m <<= 1) {
                s += __shfl_xor(s, m); ss += __shfl_xor(ss, m);
                if (SCORE) sp += __shfl_xor(sp, m);
            }
            if (lo == 0) {
                int rl = hi * 4 + q;
                part[w][rl][0] = s; part[w][rl][1] = ss;
                if (SCORE) part[w][rl][2] = sp;
            }
        }
        __syncthreads();
        if (tid < 16) {
            float s = 0.f, ss = 0.f, sp = 0.f;
#pragma unroll
            for (int w2 = 0; w2 < 4; ++w2) {
                s += part[w2][tid][0]; ss += part[w2][tid][1];
                if (SCORE) sp += part[w2][tid][2];
            }
            float mean = s * (1.0f / DD);
            float var = ss * (1.0f / DD) - mean * mean;
            mrs[tid][0] = mean;
            mrs[tid][1] = rsqrtf(var + 1e-5f);
            if (SCORE) {
                int r = rowBase + tid;
                int b2 = r / n, ii = r - b2 * n;
                scores[b2 * NTOT + ii] = sp * pinv_all[dep];
            }
        }
        __syncthreads();
#pragma unroll
        for (int q = 0; q < 4; ++q) {
            int rl = hi * 4 + q;
            int r = rowBase + rl;
            float mean = mrs[rl][0], rs = mrs[rl][1];
#pragma unroll
            for (int j = 0; j < 4; ++j) {
                int c = w * 64 + j * 16 + lo;
                float v = vh[j][q];
                h[(size_t)r * DD + c] = v;
                zout[(size_t)r * DD + c] = (v - mean) * rs;
            }
        }
    }
}

// ---------------- standalone mm for positional embedding (16 rows/block) ----------------
__global__ void __launch_bounds__(256) mm_pe_kernel(const half_t* __restrict__ A,
                                                    const half_t* __restrict__ Wt,
                                                    const float* __restrict__ bias,
                                                    float* __restrict__ C) {
    int tid = threadIdx.x;
    int w = tid >> 6, l = tid & 63;
    int lo = l & 15, hi = l >> 4;
    int rowBase = blockIdx.x * 16;
    int kb = hi * 8;
    const half_t* a0p = A + (size_t)(rowBase + lo) * DD + kb;
    f32x4 acc[4] = {};
#pragma unroll
    for (int k0 = 0; k0 < DD; k0 += 32) {
        halfx8 a0 = *(const halfx8*)(a0p + k0);
#pragma unroll
        for (int j = 0; j < 4; ++j) {
            halfx8 bj = *(const halfx8*)(Wt + (size_t)(w * 64 + j * 16 + lo) * DD + kb + k0);
            acc[j] = __builtin_amdgcn_mfma_f32_16x16x32_f16(a0, bj, acc[j], 0, 0, 0);
        }
    }
#pragma unroll
    for (int q = 0; q < 4; ++q)
#pragma unroll
        for (int j = 0; j < 4; ++j) {
            int r = rowBase + hi * 4 + q;
            int c = w * 64 + j * 16 + lo;
            C[(size_t)r * DD + c] = acc[j][q] + bias[c];
        }
}

// ---------------- pooling: 1-pass radix + candidate rank (fallback: full radix) ----------------
__global__ void topk_kernel(const float* __restrict__ scores, const int* __restrict__ orig_cur,
                            int* __restrict__ orig_next, int* __restrict__ idx_local,
                            float* __restrict__ gate, int n, int k) {
    __shared__ unsigned keys[2048];
    __shared__ int hist[256];
    __shared__ int sg[256], se[256];
    __shared__ int sh_bucket, sh_r, sh_cnt;
    __shared__ unsigned cand[256];
    __shared__ unsigned sh_thr;
    int b = blockIdx.x;
    const float* sc = scores + b * NTOT;
    int tid = threadIdx.x;
    for (int i = tid; i < n; i += 256) {
        unsigned u = __float_as_uint(sc[i]);
        keys[i] = (u & 0x80000000u) ? ~u : (u | 0x80000000u);
    }
    hist[tid] = 0;
    if (tid == 0) sh_cnt = 0;
    __syncthreads();
    for (int i = tid; i < n; i += 256) atomicAdd(&hist[keys[i] >> 24], 1);
    __syncthreads();
    int cnt = hist[tid];
    sg[tid] = cnt;
    __syncthreads();
    for (int off = 1; off < 256; off <<= 1) {
        int v = (tid >= off) ? sg[tid - off] : 0;
        __syncthreads();
        sg[tid] += v;
        __syncthreads();
    }
    int r = n - k;  // 0-indexed rank ascending
    int incl = sg[tid], excl = incl - cnt;
    if (excl <= r && r < incl) { sh_bucket = tid; sh_r = r - excl; }
    __syncthreads();
    int b1 = sh_bucket, r1 = sh_r;
    int c = hist[b1];
    unsigned thrkey;
    if (c <= 256) {
        // gather candidates, rank by counting (no more passes)
        for (int i = tid; i < n; i += 256) {
            unsigned key = keys[i];
            if ((key >> 24) == (unsigned)b1) {
                int pos = atomicAdd(&sh_cnt, 1);
                cand[pos] = key;
            }
        }
        __syncthreads();
        if (tid < c) {
            unsigned mine = cand[tid];
            int less = 0, eq = 0;
            for (int j = 0; j < c; ++j) {
                unsigned oth = cand[j];
                less += (oth < mine); eq += (oth == mine);
            }
            if (less <= r1 && r1 < less + eq) sh_thr = mine;
        }
        __syncthreads();
        thrkey = sh_thr;
    } else {
        unsigned prefix = ((unsigned)b1) << 24;
        int rr = r1;
        for (int shift = 16; shift >= 0; shift -= 8) {
            __syncthreads();
            hist[tid] = 0;
            __syncthreads();
            unsigned mask = 0xFFFFFFFFu << (shift + 8);
            for (int i = tid; i < n; i += 256) {
                unsigned key = keys[i];
                if ((key & mask) == (prefix & mask)) atomicAdd(&hist[(key >> shift) & 255], 1);
            }
            __syncthreads();
            int cnt2 = hist[tid];
            sg[tid] = cnt2;
            __syncthreads();
            for (int off = 1; off < 256; off <<= 1) {
                int v = (tid >= off) ? sg[tid - off] : 0;
                __syncthreads();
                sg[tid] += v;
                __syncthreads();
            }
            int incl2 = sg[tid], excl2 = incl2 - cnt2;
            if (excl2 <= rr && rr < incl2) { sh_bucket = tid; sh_r = rr - excl2; }
            __syncthreads();
            prefix |= ((unsigned)sh_bucket) << shift;
            rr = sh_r;
            __syncthreads();
        }
        thrkey = prefix;
    }
    unsigned uthr = (thrkey & 0x80000000u) ? (thrkey ^ 0x80000000u) : ~thrkey;
    float thr = __uint_as_float(uthr);  // exact k-th largest value
    // tie-aware stable compaction (identical semantics to jax top_k + sort)
    int chunk = n / 256;
    int base = tid * chunk;
    int cgt = 0, ceq = 0;
    for (int u = 0; u < chunk; ++u) {
        float s = sc[base + u];
        cgt += (s > thr); ceq += (s == thr);
    }
    sg[tid] = cgt; se[tid] = ceq; __syncthreads();
    for (int off = 1; off < 256; off <<= 1) {
        int vg = (tid >= off) ? sg[tid - off] : 0;
        int ve = (tid >= off) ? se[tid - off] : 0;
        __syncthreads();
        sg[tid] += vg; se[tid] += ve;
        __syncthreads();
    }
    int total_gt = sg[255];
    int ties = k - total_gt;
    int gtb = sg[tid] - cgt, eqb = se[tid] - ceq;
    for (int u = 0; u < chunk; ++u) {
        int i = base + u;
        float s = sc[i];
        bool isgt = (s > thr), iseq = (s == thr);
        bool keep = isgt || (iseq && eqb < ties);
        if (keep) {
            int pos = gtb + (eqb < ties ? eqb : ties);
            idx_local[b * NTOT + pos] = i;
            gate[b * NTOT + pos] = tanhf(s);
            orig_next[b * NTOT + pos] = orig_cur[b * NTOT + i];
        }
        gtb += isgt; eqb += iseq;
    }
}

// gather gated rows, recompute stats, write z, and set inverse map
__global__ void __launch_bounds__(64) gather_kernel(
    const float* __restrict__ h, const int* __restrict__ idx_local,
    const float* __restrict__ gate, const int* __restrict__ orig_new,
    float* __restrict__ hout, float* __restrict__ zout, int* __restrict__ inv,
    int n_old, int k, int tag) {
    int r = blockIdx.x;  // B*k
    int b = r / k, rr = r - b * k;
    int lane = threadIdx.x;
    int src = idx_local[b * NTOT + rr];
    float gg = gate[b * NTOT + rr];
    f32x4 v = ((const f32x4*)h)[(size_t)(b * n_old + src) * 64 + lane] * gg;
    ((f32x4*)hout)[(size_t)r * 64 + lane] = v;
    float s = v[0] + v[1] + v[2] + v[3];
    float ss = v[0] * v[0] + v[1] * v[1] + v[2] * v[2] + v[3] * v[3];
#pragma unroll
    for (int m = 1; m < 64; m <<= 1) { s += __shfl_xor(s, m); ss += __shfl_xor(ss, m); }
    float mean = s * (1.0f / DD);
    float rs = rsqrtf(ss * (1.0f / DD) - mean * mean + 1e-5f);
    f32x4 zv = (v - mean) * rs;
    ((f32x4*)zout)[(size_t)r * 64 + lane] = zv;
    if (lane == 0) inv[b * NTOT + orig_new[b * NTOT + rr]] = (tag << 12) | rr;
}

// ---------------- readout ----------------
__global__ void readout_kernel(const float* __restrict__ h, float* __restrict__ feat) {
    int bd = blockIdx.x;  // B*256
    int b = bd >> 8, d = bd & 255;
    int i = threadIdx.x;
    float x = h[(size_t)(b * 256 + i) * DD + d];
    float m = blockReduceSum256(x) / 256.0f;
    float diff = x - m;
    float s2 = blockReduceSum256(diff * diff);
    if (i == 0) {
        feat[b * 512 + d] = m;
        feat[b * 512 + 256 + d] = sqrtf(s2 / 255.0f) + 1e-6f;
    }
}

__global__ void final_kernel(const float* __restrict__ feat, const float* __restrict__ lw,
                             const float* __restrict__ lb, float* __restrict__ out) {
    int b = blockIdx.x, l = threadIdx.x;  // 128 threads
    float acc = lb[l];
    const float* f = feat + b * 512;
    for (int k = 0; k < 512; ++k) acc += f[k] * lw[k * 128 + l];
    out[b * 128 + l] = acc;
}

extern "C" void kernel_launch(void* const* d_in, const int* in_sizes, int n_in,
                              void* d_out, int out_size, void* d_ws, size_t ws_size,
                              hipStream_t stream) {
    (void)in_sizes; (void)n_in; (void)out_size; (void)ws_size;
    const float* x     = (const float*)d_in[0];
    const float* adj   = (const float*)d_in[1];
    const float* pos   = (const float*)d_in[2];
    const float* in_w  = (const float*)d_in[3];
    const float* in_b  = (const float*)d_in[4];
    const float* pw1   = (const float*)d_in[5];
    const float* pb1   = (const float*)d_in[6];
    const float* pw2   = (const float*)d_in[7];
    const float* pb2   = (const float*)d_in[8];
    const float* bg    = (const float*)d_in[9];
    const float* bb    = (const float*)d_in[10];
    const float* bw1   = (const float*)d_in[11];
    const float* bb1   = (const float*)d_in[12];
    const float* bw2   = (const float*)d_in[13];
    const float* bb2   = (const float*)d_in[14];
    const float* beps  = (const float*)d_in[15];
    const float* poolp = (const float*)d_in[16];
    const float* lw    = (const float*)d_in[17];
    const float* lb    = (const float*)d_in[18];
    float* out = (float*)d_out;

    char* wp = (char*)d_ws;
    auto alloc = [&](size_t bytes) -> void* {
        void* p = (void*)wp;
        wp += (bytes + 255) & ~(size_t)255;
        return p;
    };
    const size_t HBYTES = (size_t)BSZ * NTOT * DD * sizeof(float);  // 8.39 MB
    float*  h    = (float*)alloc(HBYTES);
    float*  bufC = (float*)alloc(HBYTES);          // pe out / gather target
    float*  zA   = (float*)alloc(HBYTES);
    float*  zB   = (float*)alloc(HBYTES);
    half_t* tbq  = (half_t*)alloc((size_t)NTOT * DD * sizeof(half_t));
    half_t* Wt   = (half_t*)alloc((size_t)17 * DD * DD * sizeof(half_t));
    float* pstats  = (float*)alloc(8 * sizeof(float));
    float* pinv    = (float*)alloc(4 * sizeof(float));
    float* scores  = (float*)alloc(BSZ * NTOT * sizeof(float));
    float* gate    = (float*)alloc(BSZ * NTOT * sizeof(float));
    int*   origA   = (int*)alloc(BSZ * NTOT * sizeof(int));
    int*   origB   = (int*)alloc(BSZ * NTOT * sizeof(int));
    int*   idxl    = (int*)alloc(BSZ * NTOT * sizeof(int));
    int*   inv     = (int*)alloc(BSZ * NTOT * sizeof(int));
    int*   counts  = (int*)alloc(NTOT * sizeof(int));
    int*   row_ptr = (int*)alloc((NTOT + 1) * sizeof(int));
    int*   col     = (int*)alloc((size_t)NTOT * 64 * sizeof(int));
    int*   ldeg    = (int*)alloc(BSZ * NTOT * sizeof(int));
    int*   lcol    = (int*)alloc((size_t)BSZ * NTOT * 64 * sizeof(int));
    float* feat    = (float*)alloc(BSZ * 512 * sizeof(float));

    // ---- init ----
    wprep_kernel<<<dim3(17, 16, 16), 256, 0, stream>>>(bw1, bw2, pw2, Wt);
    stats_kernel<<<4, 256, 0, stream>>>(pos, pstats, poolp, pinv);
    pe_q_kernel<<<NTOT, 256, 0, stream>>>(pos, pstats, pw1, pb1, tbq);
    mm_pe_kernel<<<NTOT / 16, 256, 0, stream>>>(tbq, Wt + (size_t)16 * DD * DD, pb2, bufC);
    init_h_kernel<<<BSZ * NTOT, 256, 0, stream>>>(x, in_w, in_b, bufC, h, zA);
    csr_count_kernel<<<NTOT, 256, 0, stream>>>(adj, counts);
    scan_kernel<<<1, 256, 0, stream>>>(counts, row_ptr);
    csr_fill_kernel<<<NTOT, 64, 0, stream>>>(adj, row_ptr, col);
    init_maps_kernel<<<(BSZ * NTOT) / 256, 256, 0, stream>>>(origA, inv);

    float* hcur = h;
    float* halt = bufC;
    float* zin = zA;
    float* zout = zB;
    int* orig = origA;
    int* orign = origB;
    int n = NTOT;
    int blk = 0;
    for (int dep = 0; dep < 4; ++dep) {
        for (int s = 0; s < 2; ++s) {
            int rows = BSZ * n;
            if (s == 1 && dep < 3) {
                layer_kernel<1><<<rows / 16, 256, 0, stream>>>(
                    hcur, zin, zout, Wt + (size_t)blk * DD * DD, Wt + (size_t)(8 + blk) * DD * DD,
                    bb1 + blk * DD, bb2 + blk * DD, bg + blk * DD, bb + blk * DD,
                    beps, blk, row_ptr, col, ldeg, lcol, poolp, pinv, scores, dep, n,
                    dep == 0 ? 1 : 0);
            } else {
                layer_kernel<0><<<rows / 16, 256, 0, stream>>>(
                    hcur, zin, zout, Wt + (size_t)blk * DD * DD, Wt + (size_t)(8 + blk) * DD * DD,
                    bb1 + blk * DD, bb2 + blk * DD, bg + blk * DD, bb + blk * DD,
                    beps, blk, row_ptr, col, ldeg, lcol, nullptr, nullptr, nullptr, 0, n,
                    dep == 0 ? 1 : 0);
            }
            { float* t = zin; zin = zout; zout = t; }
            ++blk;
        }
        if (dep < 3) {
            int k = n / 2;
            topk_kernel<<<BSZ, 256, 0, stream>>>(scores, orig, orign, idxl, gate, n, k);
            { int* t = orig; orig = orign; orign = t; }
            gather_kernel<<<BSZ * k, 64, 0, stream>>>(hcur, idxl, gate, orig, halt, zin, inv,
                                                      n, k, dep + 1);
            { float* t = hcur; hcur = halt; halt = t; }
            build_lcol_kernel<<<(BSZ * k) / 256, 256, 0, stream>>>(row_ptr, col, orig, inv,
                                                                   ldeg, lcol, k, dep + 1);
            n = k;
        }
    }
    // ---- readout ----
    readout_kernel<<<BSZ * 256, 256, 0, stream>>>(hcur, feat);
    final_kernel<<<BSZ, 128, 0, stream>>>(feat, lw, lb, out);
}

// Round 8
// 283.307 us; speedup vs baseline: 1.3662x; 1.0405x over previous
//
#include <hip/hip_runtime.h>
#include <hip/hip_bf16.h>

#define NTOT 2048
#define DD 256
#define BSZ 4

typedef _Float16 half_t;
typedef __attribute__((ext_vector_type(8))) _Float16 halfx8;
typedef __attribute__((ext_vector_type(4))) _Float16 halfx4;
typedef __attribute__((ext_vector_type(4))) float f32x4;

// ---------------- block reduce (256 threads) ----------------
__device__ __forceinline__ float blockReduceSum256(float v) {
    __shared__ float red[4];
    for (int off = 32; off > 0; off >>= 1) v += __shfl_down(v, off);
    int lane = threadIdx.x & 63, w = threadIdx.x >> 6;
    __syncthreads();
    if (lane == 0) red[w] = v;
    __syncthreads();
    return red[0] + red[1] + red[2] + red[3];
}

// ---------------- mega setup: wprep | stats | adj->lcol0 | maps ----------------
// blocks [0, 4352): weight transpose (17 matrices, 16x16 tiles)
// blocks [4352, 4356): pos stats (1) + pool norms (3)
// blocks [4356, 4868): adjacency -> padded local col list (4 rows/block)
// blocks [4868, 4900): orig/inv map init
#define SB_WPREP 4352
#define SB_STAT  4356
#define SB_A2L   4868
#define SB_MAPS  4900
__global__ void __launch_bounds__(256) setup_kernel(
    const float* __restrict__ bw1, const float* __restrict__ bw2,
    const float* __restrict__ pw2, half_t* __restrict__ Wt,
    const float* __restrict__ pos, float* __restrict__ pstats,
    const float* __restrict__ poolp, float* __restrict__ pinv,
    const float* __restrict__ adj, int* __restrict__ ldeg0, int* __restrict__ lcol0,
    int* __restrict__ orig, int* __restrict__ inv) {
    int bid = blockIdx.x, tid = threadIdx.x;
    if (bid < SB_WPREP) {
        int m = bid >> 8, rem = bid & 255;
        int nb = (rem >> 4) * 16, kb = (rem & 15) * 16;
        const float* W = (m < 8) ? (bw1 + (size_t)m * DD * DD)
                      : (m < 16) ? (bw2 + (size_t)(m - 8) * DD * DD)
                                 : pw2;
        __shared__ float s[16][17];
        int i = tid >> 4, j = tid & 15;
        s[i][j] = W[(size_t)(kb + i) * DD + nb + j];
        __syncthreads();
        Wt[(size_t)m * DD * DD + (size_t)(nb + i) * DD + kb + j] = (half_t)s[j][i];
    } else if (bid < SB_STAT) {
        int which = bid - SB_WPREP;
        if (which == 0) {
            float s[3] = {0.f, 0.f, 0.f};
            for (int i = tid; i < NTOT; i += 256)
                for (int c = 0; c < 3; ++c) s[c] += pos[i * 3 + c];
            float m[3];
            for (int c = 0; c < 3; ++c) m[c] = blockReduceSum256(s[c]) / (float)NTOT;
            float q[3] = {0.f, 0.f, 0.f};
            for (int i = tid; i < NTOT; i += 256)
                for (int c = 0; c < 3; ++c) { float d = pos[i * 3 + c] - m[c]; q[c] += d * d; }
            for (int c = 0; c < 3; ++c) {
                float t = blockReduceSum256(q[c]);
                if (tid == 0) {
                    float var = ((float)BSZ * t) / ((float)BSZ * NTOT - 1.0f);
                    pstats[c] = m[c];
                    pstats[3 + c] = 1.0f / (sqrtf(var) + 1e-8f);
                }
            }
        } else {
            int dep = which - 1;
            float v = poolp[dep * DD + tid];
            float ss = blockReduceSum256(v * v);
            if (tid == 0) pinv[dep] = rsqrtf(ss);
        }
    } else if (bid < SB_A2L) {
        int row = (bid - SB_STAT) * 4 + (tid >> 6);
        int lane = tid & 63;
        int run = 0;
        for (int j0 = 0; j0 < NTOT; j0 += 64) {
            int j = j0 + lane;
            bool pred = adj[(size_t)row * NTOT + j] != 0.f;
            unsigned long long mask = __ballot(pred);
            if (pred) {
                int pos2 = run + __popcll(mask & ((1ull << lane) - 1ull));
                if (pos2 < 64) lcol0[row * 64 + pos2] = j;
            }
            run += __popcll(mask);
        }
        if (lane == 0) ldeg0[row] = run < 64 ? run : 64;
    } else {
        int t = (bid - SB_A2L) * 256 + tid;  // B*NTOT
        int i = t & (NTOT - 1);
        orig[t] = i; inv[t] = i;  // tag 0
    }
}

// ---------------- fused pe + input projection + h/z init ----------------
// grid NTOT/16 blocks, 256 thr. Per block: 16 pe rows -> q (LDS, f16) -> MFMA vs pw2^T
// -> pe tile (regs); then for each batch replica: x-proj + pe, stats, h, z.
__global__ void __launch_bounds__(256) pe_h_kernel(
    const float* __restrict__ pos, const float* __restrict__ pstats,
    const float* __restrict__ pw1, const float* __restrict__ pb1,
    const half_t* __restrict__ Wt16, const float* __restrict__ pb2,
    const float* __restrict__ x, const float* __restrict__ in_w,
    const float* __restrict__ in_b, float* __restrict__ h, float* __restrict__ z) {
    __shared__ half_t tb[16][264];
    __shared__ float iw[16][DD];
    __shared__ float xs[16][16];
    __shared__ float part[4][16][2];
    __shared__ float mrs[16][2];
    int tid = threadIdx.x;
    int i0 = blockIdx.x * 16;
    // ---- q = silu(pn @ pw1 + pb1) -> LDS (each thread: 1 row x 16 cols) ----
    {
        int rl = tid >> 4, cb = (tid & 15) * 16;
        float pn[3];
#pragma unroll
        for (int c = 0; c < 3; ++c)
            pn[c] = (pos[(i0 + rl) * 3 + c] - pstats[c]) * pstats[3 + c];
#pragma unroll
        for (int u = 0; u < 16; ++u) {
            int d = cb + u;
            float a = pb1[d];
            a += pn[0] * pw1[d];
            a += pn[1] * pw1[DD + d];
            a += pn[2] * pw1[2 * DD + d];
            a = a / (1.0f + expf(-a));
            tb[rl][d] = (half_t)a;
        }
        // in_w -> LDS (16x256): thread loads 16
        int k = tid >> 4;
#pragma unroll
        for (int u = 0; u < 16; ++u) iw[k][cb + u] = in_w[k * DD + cb + u];
    }
    __syncthreads();
    int w = tid >> 6, l = tid & 63;
    int lo = l & 15, hi = l >> 4;
    int kb = hi * 8;
    // ---- pe = q @ pw2^T + pb2 (MFMA) ----
    float pe_r[4][4];
    {
        f32x4 acc[4] = {};
#pragma unroll
        for (int k0 = 0; k0 < DD; k0 += 32) {
            halfx8 a0 = *(const halfx8*)&tb[lo][kb + k0];
#pragma unroll
            for (int j = 0; j < 4; ++j) {
                halfx8 bj = *(const halfx8*)(Wt16 + (size_t)(w * 64 + j * 16 + lo) * DD + kb + k0);
                acc[j] = __builtin_amdgcn_mfma_f32_16x16x32_f16(a0, bj, acc[j], 0, 0, 0);
            }
        }
#pragma unroll
        for (int j = 0; j < 4; ++j) {
            float bs = pb2[w * 64 + j * 16 + lo];
#pragma unroll
            for (int q = 0; q < 4; ++q) pe_r[j][q] = acc[j][q] + bs;
        }
    }
    float xb[4];
#pragma unroll
    for (int j = 0; j < 4; ++j) xb[j] = in_b[w * 64 + j * 16 + lo];
    // ---- per batch: x-proj + pe, stats, h, z ----
    for (int b = 0; b < BSZ; ++b) {
        __syncthreads();
        xs[tid >> 4][tid & 15] = x[(size_t)(b * NTOT + i0 + (tid >> 4)) * 16 + (tid & 15)];
        __syncthreads();
        float vh[4][4];
#pragma unroll
        for (int q = 0; q < 4; ++q) {
            int rl = hi * 4 + q;
            float s = 0.f, ss = 0.f;
#pragma unroll
            for (int j = 0; j < 4; ++j) {
                int c = w * 64 + j * 16 + lo;
                float acc = xb[j];
#pragma unroll
                for (int k = 0; k < 16; ++k) acc += xs[rl][k] * iw[k][c];
                float v = acc + pe_r[j][q];
                vh[j][q] = v;
                s += v; ss += v * v;
            }
#pragma unroll
            for (int m = 1; m < 16; m <<= 1) { s += __shfl_xor(s, m); ss += __shfl_xor(ss, m); }
            if (lo == 0) { part[w][rl][0] = s; part[w][rl][1] = ss; }
        }
        __syncthreads();
        if (tid < 16) {
            float s = 0.f, ss = 0.f;
#pragma unroll
            for (int w2 = 0; w2 < 4; ++w2) { s += part[w2][tid][0]; ss += part[w2][tid][1]; }
            float mean = s * (1.0f / DD);
            float var = ss * (1.0f / DD) - mean * mean;
            mrs[tid][0] = mean;
            mrs[tid][1] = rsqrtf(var + 1e-5f);
        }
        __syncthreads();
#pragma unroll
        for (int q = 0; q < 4; ++q) {
            int rl = hi * 4 + q;
            size_t r = (size_t)(b * NTOT + i0 + rl);
            float mean = mrs[rl][0], rs = mrs[rl][1];
#pragma unroll
            for (int j = 0; j < 4; ++j) {
                int c = w * 64 + j * 16 + lo;
                float v = vh[j][q];
                h[r * DD + c] = v;
                z[r * DD + c] = (v - mean) * rs;
            }
        }
    }
}

// ---------------- fused layer: agg -> mm1+silu -> mm2 + residual/stats/z (+score) ----
// 16 rows/block, 256 thr. Phase A: 16 thr/row; lvl0 reads lcol0 directly, else
// filters lcol0[orig[r]] through inv-tag on the fly (same kept order as before).
template <int SCORE>
__global__ void __launch_bounds__(256) layer_kernel(
    float* __restrict__ h, const float* __restrict__ zin, float* __restrict__ zout,
    const half_t* __restrict__ Wt1, const half_t* __restrict__ Wt2,
    const float* __restrict__ b1v, const float* __restrict__ b2v,
    const float* __restrict__ gv, const float* __restrict__ bbv,
    const float* __restrict__ beps, int blk,
    const int* __restrict__ ldeg0, const int* __restrict__ lcol0,
    const int* __restrict__ orig, const int* __restrict__ inv,
    const float* __restrict__ poolp, const float* __restrict__ pinv_all,
    float* __restrict__ scores, int dep, int n, int tag) {
    __shared__ half_t tb[16][264];
    __shared__ half_t ub[16][264];
    __shared__ float part[4][16][3];
    __shared__ float mrs[16][2];
    int tid = threadIdx.x;
    int rowBase = blockIdx.x * 16;
    float eps1 = 1.0f + beps[blk];

    // ---- phase A: aggregation -> LDS tb (f16) ----
    {
        int rl = tid >> 4, cg = tid & 15;   // 16 thr/row, 4 f32x4 chunks each
        int r = rowBase + rl;
        int b = r / n, i = r - b * n;
        const f32x4* zb = (const f32x4*)zin + (size_t)b * n * 64;
        f32x4 acc[4];
#pragma unroll
        for (int u = 0; u < 4; ++u) acc[u] = zb[(size_t)i * 64 + cg + 16 * u] * eps1;
        int cnt = 0;
        if (tag == 0) {
            int deg = ldeg0[i];
            const int* lc = lcol0 + i * 64;
            int p = 0;
            for (; p + 4 <= deg; p += 4) {
                int j0 = lc[p], j1 = lc[p + 1], j2 = lc[p + 2], j3 = lc[p + 3];
#pragma unroll
                for (int u = 0; u < 4; ++u) {
                    f32x4 v0 = zb[(size_t)j0 * 64 + cg + 16 * u];
                    f32x4 v1 = zb[(size_t)j1 * 64 + cg + 16 * u];
                    f32x4 v2 = zb[(size_t)j2 * 64 + cg + 16 * u];
                    f32x4 v3 = zb[(size_t)j3 * 64 + cg + 16 * u];
                    acc[u] += (v0 + v1) + (v2 + v3);
                }
            }
            for (; p < deg; ++p) {
                int j = lc[p];
#pragma unroll
                for (int u = 0; u < 4; ++u) acc[u] += zb[(size_t)j * 64 + cg + 16 * u];
            }
            cnt = deg;
        } else {
            int o = orig[b * NTOT + i];
            int deg = ldeg0[o];
            const int* lc = lcol0 + o * 64;
            const int* invb = inv + b * NTOT;
            int p = 0;
            for (; p + 4 <= deg; p += 4) {
                int c0 = lc[p], c1 = lc[p + 1], c2 = lc[p + 2], c3 = lc[p + 3];
                int v0 = invb[c0], v1 = invb[c1], v2 = invb[c2], v3 = invb[c3];
                if ((v0 >> 12) == tag) {
                    int j = v0 & 4095; ++cnt;
#pragma unroll
                    for (int u = 0; u < 4; ++u) acc[u] += zb[(size_t)j * 64 + cg + 16 * u];
                }
                if ((v1 >> 12) == tag) {
                    int j = v1 & 4095; ++cnt;
#pragma unroll
                    for (int u = 0; u < 4; ++u) acc[u] += zb[(size_t)j * 64 + cg + 16 * u];
                }
                if ((v2 >> 12) == tag) {
                    int j = v2 & 4095; ++cnt;
#pragma unroll
                    for (int u = 0; u < 4; ++u) acc[u] += zb[(size_t)j * 64 + cg + 16 * u];
                }
                if ((v3 >> 12) == tag) {
                    int j = v3 & 4095; ++cnt;
#pragma unroll
                    for (int u = 0; u < 4; ++u) acc[u] += zb[(size_t)j * 64 + cg + 16 * u];
                }
            }
            for (; p < deg; ++p) {
                int v = invb[lc[p]];
                if ((v >> 12) == tag) {
                    int j = v & 4095; ++cnt;
#pragma unroll
                    for (int u = 0; u < 4; ++u) acc[u] += zb[(size_t)j * 64 + cg + 16 * u];
                }
            }
        }
        float coefb = eps1 + (float)cnt;
#pragma unroll
        for (int u = 0; u < 4; ++u) {
            int c4 = cg + 16 * u;
            f32x4 gvv = ((const f32x4*)gv)[c4];
            f32x4 bvv = ((const f32x4*)bbv)[c4];
            f32x4 tv = gvv * acc[u] + bvv * coefb;
            halfx4 th;
#pragma unroll
            for (int e = 0; e < 4; ++e) th[e] = (half_t)tv[e];
            *(halfx4*)&tb[rl][c4 * 4] = th;
        }
    }
    __syncthreads();

    int w = tid >> 6, l = tid & 63;
    int lo = l & 15, hi = l >> 4;
    int kb = hi * 8;

    // ---- phase B: mm1 + silu -> ub ----
    {
        f32x4 acc[4] = {};
#pragma unroll
        for (int k0 = 0; k0 < DD; k0 += 32) {
            halfx8 a0 = *(const halfx8*)&tb[lo][kb + k0];
#pragma unroll
            for (int j = 0; j < 4; ++j) {
                halfx8 bj = *(const halfx8*)(Wt1 + (size_t)(w * 64 + j * 16 + lo) * DD + kb + k0);
                acc[j] = __builtin_amdgcn_mfma_f32_16x16x32_f16(a0, bj, acc[j], 0, 0, 0);
            }
        }
        float bs[4];
#pragma unroll
        for (int j = 0; j < 4; ++j) bs[j] = b1v[w * 64 + j * 16 + lo];
#pragma unroll
        for (int q = 0; q < 4; ++q)
#pragma unroll
            for (int j = 0; j < 4; ++j) {
                float v = acc[j][q] + bs[j];
                v = v / (1.0f + expf(-v));
                ub[hi * 4 + q][w * 64 + j * 16 + lo] = (half_t)v;
            }
    }
    __syncthreads();

    // ---- phase C: mm2 + residual + stats (+score) + z ----
    {
        f32x4 acc[4] = {};
#pragma unroll
        for (int k0 = 0; k0 < DD; k0 += 32) {
            halfx8 a0 = *(const halfx8*)&ub[lo][kb + k0];
#pragma unroll
            for (int j = 0; j < 4; ++j) {
                halfx8 bj = *(const halfx8*)(Wt2 + (size_t)(w * 64 + j * 16 + lo) * DD + kb + k0);
                acc[j] = __builtin_amdgcn_mfma_f32_16x16x32_f16(a0, bj, acc[j], 0, 0, 0);
            }
        }
        float bs[4], pv[4] = {};
#pragma unroll
        for (int j = 0; j < 4; ++j) bs[j] = b2v[w * 64 + j * 16 + lo];
        if (SCORE) {
#pragma unroll
            for (int j = 0; j < 4; ++j) pv[j] = poolp[dep * DD + w * 64 + j * 16 + lo];
        }
        float vh[4][4];
#pragma unroll
        for (int q = 0; q < 4; ++q) {
            int r = rowBase + hi * 4 + q;
            float s = 0.f, ss = 0.f, sp = 0.f;
#pragma unroll
            for (int j = 0; j < 4; ++j) {
                int c = w * 64 + j * 16 + lo;
                float v = h[(size_t)r * DD + c] + acc[j][q] + bs[j];
                vh[j][q] = v;
                s += v; ss += v * v;
                if (SCORE) sp += v * pv[j];
            }
#pragma unroll
            for (int m = 1; m < 16; m <<= 1) {
                s += __shfl_xor(s, m); ss += __shfl_xor(ss, m);
                if (SCORE) sp += __shfl_xor(sp, m);
            }
            if (lo == 0) {
                int rl = hi * 4 + q;
                part[w][rl][0] = s; part[w][rl][1] = ss;
                if (SCORE) part[w][rl][2] = sp;
            }
        }
        __syncthreads();
        if (tid < 16) {
            float s = 0.f, ss = 0.f, sp = 0.f;
#pragma unroll
            for (int w2 = 0; w2 < 4; ++w2) {
                s += part[w2][tid][0]; ss += part[w2][tid][1];
                if (SCORE) sp += part[w2][tid][2];
            }
            float mean = s * (1.0f / DD);
            float var = ss * (1.0f / DD) - mean * mean;
            mrs[tid][0] = mean;
            mrs[tid][1] = rsqrtf(var + 1e-5f);
            if (SCORE) {
                int r = rowBase + tid;
                int b2 = r / n, ii = r - b2 * n;
                scores[b2 * NTOT + ii] = sp * pinv_all[dep];
            }
        }
        __syncthreads();
#pragma unroll
        for (int q = 0; q < 4; ++q) {
            int rl = hi * 4 + q;
            int r = rowBase + rl;
            float mean = mrs[rl][0], rs = mrs[rl][1];
#pragma unroll
            for (int j = 0; j < 4; ++j) {
                int c = w * 64 + j * 16 + lo;
                float v = vh[j][q];
                h[(size_t)r * DD + c] = v;
                zout[(size_t)r * DD + c] = (v - mean) * rs;
            }
        }
    }
}

// ---------------- pooling: 1-pass radix + candidate rank (fallback: full radix) ----------------
__global__ void topk_kernel(const float* __restrict__ scores, const int* __restrict__ orig_cur,
                            int* __restrict__ orig_next, int* __restrict__ idx_local,
                            float* __restrict__ gate, int n, int k) {
    __shared__ unsigned keys[2048];
    __shared__ int hist[256];
    __shared__ int sg[256], se[256];
    __shared__ int sh_bucket, sh_r, sh_cnt;
    __shared__ unsigned cand[256];
    __shared__ unsigned sh_thr;
    int b = blockIdx.x;
    const float* sc = scores + b * NTOT;
    int tid = threadIdx.x;
    for (int i = tid; i < n; i += 256) {
        unsigned u = __float_as_uint(sc[i]);
        keys[i] = (u & 0x80000000u) ? ~u : (u | 0x80000000u);
    }
    hist[tid] = 0;
    if (tid == 0) sh_cnt = 0;
    __syncthreads();
    for (int i = tid; i < n; i += 256) atomicAdd(&hist[keys[i] >> 24], 1);
    __syncthreads();
    int cnt = hist[tid];
    sg[tid] = cnt;
    __syncthreads();
    for (int off = 1; off < 256; off <<= 1) {
        int v = (tid >= off) ? sg[tid - off] : 0;
        __syncthreads();
        sg[tid] += v;
        __syncthreads();
    }
    int r = n - k;  // 0-indexed rank ascending
    int incl = sg[tid], excl = incl - cnt;
    if (excl <= r && r < incl) { sh_bucket = tid; sh_r = r - excl; }
    __syncthreads();
    int b1 = sh_bucket, r1 = sh_r;
    int c = hist[b1];
    unsigned thrkey;
    if (c <= 256) {
        for (int i = tid; i < n; i += 256) {
            unsigned key = keys[i];
            if ((key >> 24) == (unsigned)b1) {
                int pos = atomicAdd(&sh_cnt, 1);
                cand[pos] = key;
            }
        }
        __syncthreads();
        if (tid < c) {
            unsigned mine = cand[tid];
            int less = 0, eq = 0;
            for (int j = 0; j < c; ++j) {
                unsigned oth = cand[j];
                less += (oth < mine); eq += (oth == mine);
            }
            if (less <= r1 && r1 < less + eq) sh_thr = mine;
        }
        __syncthreads();
        thrkey = sh_thr;
    } else {
        unsigned prefix = ((unsigned)b1) << 24;
        int rr = r1;
        for (int shift = 16; shift >= 0; shift -= 8) {
            __syncthreads();
            hist[tid] = 0;
            __syncthreads();
            unsigned mask = 0xFFFFFFFFu << (shift + 8);
            for (int i = tid; i < n; i += 256) {
                unsigned key = keys[i];
                if ((key & mask) == (prefix & mask)) atomicAdd(&hist[(key >> shift) & 255], 1);
            }
            __syncthreads();
            int cnt2 = hist[tid];
            sg[tid] = cnt2;
            __syncthreads();
            for (int off = 1; off < 256; off <<= 1) {
                int v = (tid >= off) ? sg[tid - off] : 0;
                __syncthreads();
                sg[tid] += v;
                __syncthreads();
            }
            int incl2 = sg[tid], excl2 = incl2 - cnt2;
            if (excl2 <= rr && rr < incl2) { sh_bucket = tid; sh_r = rr - excl2; }
            __syncthreads();
            prefix |= ((unsigned)sh_bucket) << shift;
            rr = sh_r;
            __syncthreads();
        }
        thrkey = prefix;
    }
    unsigned uthr = (thrkey & 0x80000000u) ? (thrkey ^ 0x80000000u) : ~thrkey;
    float thr = __uint_as_float(uthr);  // exact k-th largest value
    int chunk = n / 256;
    int base = tid * chunk;
    int cgt = 0, ceq = 0;
    for (int u = 0; u < chunk; ++u) {
        float s = sc[base + u];
        cgt += (s > thr); ceq += (s == thr);
    }
    sg[tid] = cgt; se[tid] = ceq; __syncthreads();
    for (int off = 1; off < 256; off <<= 1) {
        int vg = (tid >= off) ? sg[tid - off] : 0;
        int ve = (tid >= off) ? se[tid - off] : 0;
        __syncthreads();
        sg[tid] += vg; se[tid] += ve;
        __syncthreads();
    }
    int total_gt = sg[255];
    int ties = k - total_gt;
    int gtb = sg[tid] - cgt, eqb = se[tid] - ceq;
    for (int u = 0; u < chunk; ++u) {
        int i = base + u;
        float s = sc[i];
        bool isgt = (s > thr), iseq = (s == thr);
        bool keep = isgt || (iseq && eqb < ties);
        if (keep) {
            int pos = gtb + (eqb < ties ? eqb : ties);
            idx_local[b * NTOT + pos] = i;
            gate[b * NTOT + pos] = tanhf(s);
            orig_next[b * NTOT + pos] = orig_cur[b * NTOT + i];
        }
        gtb += isgt; eqb += iseq;
    }
}

// gather gated rows, recompute stats, write z, and set inverse map
__global__ void __launch_bounds__(64) gather_kernel(
    const float* __restrict__ h, const int* __restrict__ idx_local,
    const float* __restrict__ gate, const int* __restrict__ orig_new,
    float* __restrict__ hout, float* __restrict__ zout, int* __restrict__ inv,
    int n_old, int k, int tag) {
    int r = blockIdx.x;  // B*k
    int b = r / k, rr = r - b * k;
    int lane = threadIdx.x;
    int src = idx_local[b * NTOT + rr];
    float gg = gate[b * NTOT + rr];
    f32x4 v = ((const f32x4*)h)[(size_t)(b * n_old + src) * 64 + lane] * gg;
    ((f32x4*)hout)[(size_t)r * 64 + lane] = v;
    float s = v[0] + v[1] + v[2] + v[3];
    float ss = v[0] * v[0] + v[1] * v[1] + v[2] * v[2] + v[3] * v[3];
#pragma unroll
    for (int m = 1; m < 64; m <<= 1) { s += __shfl_xor(s, m); ss += __shfl_xor(ss, m); }
    float mean = s * (1.0f / DD);
    float rs = rsqrtf(ss * (1.0f / DD) - mean * mean + 1e-5f);
    f32x4 zv = (v - mean) * rs;
    ((f32x4*)zout)[(size_t)r * 64 + lane] = zv;
    if (lane == 0) inv[b * NTOT + orig_new[b * NTOT + rr]] = (tag << 12) | rr;
}

// ---------------- fused readout + final projection (4 blocks) ----------------
__global__ void __launch_bounds__(256) readout_final_kernel(
    const float* __restrict__ h, const float* __restrict__ lw,
    const float* __restrict__ lb, float* __restrict__ out) {
    __shared__ float feat[512];
    int b = blockIdx.x, d = threadIdx.x;
    const float* hb = h + (size_t)b * 256 * DD;
    float s = 0.f;
    for (int i = 0; i < 256; ++i) s += hb[(size_t)i * DD + d];
    float mean = s / 256.0f;
    float s2 = 0.f;
    for (int i = 0; i < 256; ++i) {
        float diff = hb[(size_t)i * DD + d] - mean;
        s2 += diff * diff;
    }
    feat[d] = mean;
    feat[256 + d] = sqrtf(s2 / 255.0f) + 1e-6f;
    __syncthreads();
    if (d < 128) {
        float acc = lb[d];
        for (int k = 0; k < 512; ++k) acc += feat[k] * lw[k * 128 + d];
        out[b * 128 + d] = acc;
    }
}

extern "C" void kernel_launch(void* const* d_in, const int* in_sizes, int n_in,
                              void* d_out, int out_size, void* d_ws, size_t ws_size,
                              hipStream_t stream) {
    (void)in_sizes; (void)n_in; (void)out_size; (void)ws_size;
    const float* x     = (const float*)d_in[0];
    const float* adj   = (const float*)d_in[1];
    const float* pos   = (const float*)d_in[2];
    const float* in_w  = (const float*)d_in[3];
    const float* in_b  = (const float*)d_in[4];
    const float* pw1   = (const float*)d_in[5];
    const float* pb1   = (const float*)d_in[6];
    const float* pw2   = (const float*)d_in[7];
    const float* pb2   = (const float*)d_in[8];
    const float* bg    = (const float*)d_in[9];
    const float* bb    = (const float*)d_in[10];
    const float* bw1   = (const float*)d_in[11];
    const float* bb1   = (const float*)d_in[12];
    const float* bw2   = (const float*)d_in[13];
    const float* bb2   = (const float*)d_in[14];
    const float* beps  = (const float*)d_in[15];
    const float* poolp = (const float*)d_in[16];
    const float* lw    = (const float*)d_in[17];
    const float* lb    = (const float*)d_in[18];
    float* out = (float*)d_out;

    char* wp = (char*)d_ws;
    auto alloc = [&](size_t bytes) -> void* {
        void* p = (void*)wp;
        wp += (bytes + 255) & ~(size_t)255;
        return p;
    };
    const size_t HBYTES = (size_t)BSZ * NTOT * DD * sizeof(float);  // 8.39 MB
    float*  h    = (float*)alloc(HBYTES);
    float*  bufC = (float*)alloc(HBYTES);          // gather target
    float*  zA   = (float*)alloc(HBYTES);
    float*  zB   = (float*)alloc(HBYTES);
    half_t* Wt   = (half_t*)alloc((size_t)17 * DD * DD * sizeof(half_t));
    float* pstats  = (float*)alloc(8 * sizeof(float));
    float* pinv    = (float*)alloc(4 * sizeof(float));
    float* scores  = (float*)alloc(BSZ * NTOT * sizeof(float));
    float* gate    = (float*)alloc(BSZ * NTOT * sizeof(float));
    int*   origA   = (int*)alloc(BSZ * NTOT * sizeof(int));
    int*   origB   = (int*)alloc(BSZ * NTOT * sizeof(int));
    int*   idxl    = (int*)alloc(BSZ * NTOT * sizeof(int));
    int*   inv     = (int*)alloc(BSZ * NTOT * sizeof(int));
    int*   ldeg0   = (int*)alloc(NTOT * sizeof(int));
    int*   lcol0   = (int*)alloc((size_t)NTOT * 64 * sizeof(int));

    // ---- init: 2 dispatches ----
    setup_kernel<<<SB_MAPS, 256, 0, stream>>>(bw1, bw2, pw2, Wt, pos, pstats, poolp, pinv,
                                              adj, ldeg0, lcol0, origA, inv);
    pe_h_kernel<<<NTOT / 16, 256, 0, stream>>>(pos, pstats, pw1, pb1,
                                               Wt + (size_t)16 * DD * DD, pb2,
                                               x, in_w, in_b, h, zA);

    float* hcur = h;
    float* halt = bufC;
    float* zin = zA;
    float* zout = zB;
    int* orig = origA;
    int* orign = origB;
    int n = NTOT;
    int blk = 0;
    for (int dep = 0; dep < 4; ++dep) {
        for (int s = 0; s < 2; ++s) {
            int rows = BSZ * n;
            if (s == 1 && dep < 3) {
                layer_kernel<1><<<rows / 16, 256, 0, stream>>>(
                    hcur, zin, zout, Wt + (size_t)blk * DD * DD, Wt + (size_t)(8 + blk) * DD * DD,
                    bb1 + blk * DD, bb2 + blk * DD, bg + blk * DD, bb + blk * DD,
                    beps, blk, ldeg0, lcol0, orig, inv, poolp, pinv, scores, dep, n, dep);
            } else {
                layer_kernel<0><<<rows / 16, 256, 0, stream>>>(
                    hcur, zin, zout, Wt + (size_t)blk * DD * DD, Wt + (size_t)(8 + blk) * DD * DD,
                    bb1 + blk * DD, bb2 + blk * DD, bg + blk * DD, bb + blk * DD,
                    beps, blk, ldeg0, lcol0, orig, inv, nullptr, nullptr, nullptr, 0, n, dep);
            }
            { float* t = zin; zin = zout; zout = t; }
            ++blk;
        }
        if (dep < 3) {
            int k = n / 2;
            topk_kernel<<<BSZ, 256, 0, stream>>>(scores, orig, orign, idxl, gate, n, k);
            { int* t = orig; orig = orign; orign = t; }
            gather_kernel<<<BSZ * k, 64, 0, stream>>>(hcur, idxl, gate, orig, halt, zin, inv,
                                                      n, k, dep + 1);
            { float* t = hcur; hcur = halt; halt = t; }
            n = k;
        }
    }
    // ---- readout + final ----
    readout_final_kernel<<<BSZ, 256, 0, stream>>>(hcur, lw, lb, out);
}